// Round 2
// baseline (6067.579 us; speedup 1.0000x reference)
//
#include <hip/hip_runtime.h>
#include <math.h>

#define N_ATOMS   100000
#define ATOM_FDIM 133
#define HIDDEN    512
#define MAX_NEI   6
#define N_MOLS    4096
#define N_PAIRS   8192

// bf16 <-> fp32 helpers (RNE; inputs are well-scaled, no NaN/Inf in this net)
static __device__ __forceinline__ float bf2f(unsigned short h) {
    return __uint_as_float(((unsigned int)h) << 16);
}
static __device__ __forceinline__ unsigned short f2bf(float f) {
    unsigned int u = __float_as_uint(f);
    u += 0x7FFFu + ((u >> 16) & 1u);   // round-to-nearest-even
    return (unsigned short)(u >> 16);
}

// ---------------------------------------------------------------------------
// Concat-K fp32 GEMM: C = act( A1@B1 [+ A2@B2] [+ bias] )
//   A1: fp32 [M,K1] row-major; A2: bf16 [M,K2] row-major (optional)
//   B1: fp32 [K1,N]; B2: fp32 [K2,N]; C: fp32 or bf16 [M,N]
// 128x128 tile, BK=8, 256 threads, 8x8 micro-tile (2x 4-row/4-col groups).
// ---------------------------------------------------------------------------
template<bool RELU, bool HAS_BIAS, bool HAS_A2, bool C_BF16>
__global__ __launch_bounds__(256)
void gemm2_kernel(const float* __restrict__ A1, const unsigned short* __restrict__ A2,
                  const float* __restrict__ B1, const float* __restrict__ B2,
                  const float* __restrict__ bias, void* __restrict__ Cv,
                  int M, int N, int K1, int K2)
{
    constexpr int BM = 128, BN = 128, BK = 8;
    __shared__ float As[BK][BM];
    __shared__ float Bs[BK][BN];
    const int tid  = threadIdx.x;
    const int row0 = blockIdx.y * BM;
    const int col0 = blockIdx.x * BN;
    const int tx   = tid & 15;
    const int ty   = tid >> 4;
    const int Ktot = K1 + (HAS_A2 ? K2 : 0);

    float acc[8][8];
#pragma unroll
    for (int i = 0; i < 8; ++i)
#pragma unroll
        for (int j = 0; j < 8; ++j) acc[i][j] = 0.f;

    for (int k0 = 0; k0 < Ktot; k0 += BK) {
        // stage A tile (128 x 8) transposed -> As[k][m]
#pragma unroll
        for (int i = 0; i < 4; ++i) {
            int idx = tid + i * 256;           // 0..1023
            int m = idx >> 3, k = idx & 7;
            int r = row0 + m, g = k0 + k;
            float v = 0.f;
            if (r < M && g < Ktot) {
                if (g < K1) v = A1[(size_t)r * K1 + g];
                else if (HAS_A2) v = bf2f(A2[(size_t)r * K2 + (g - K1)]);
            }
            As[k][m] = v;
        }
        // stage B tile (8 x 128)
#pragma unroll
        for (int i = 0; i < 4; ++i) {
            int idx = tid + i * 256;
            int k = idx >> 7, n = idx & 127;
            int g = k0 + k, c = col0 + n;
            float v = 0.f;
            if (g < Ktot && c < N) {
                if (g < K1) v = B1[(size_t)g * N + c];
                else if (HAS_A2) v = B2[(size_t)(g - K1) * N + c];
            }
            Bs[k][n] = v;
        }
        __syncthreads();
#pragma unroll
        for (int kk = 0; kk < BK; ++kk) {
            float a[8], b[8];
#pragma unroll
            for (int i = 0; i < 4; ++i) {
                a[i]     = As[kk][ty * 4 + i];
                a[4 + i] = As[kk][64 + ty * 4 + i];
                b[i]     = Bs[kk][tx * 4 + i];
                b[4 + i] = Bs[kk][64 + tx * 4 + i];
            }
#pragma unroll
            for (int i = 0; i < 8; ++i)
#pragma unroll
                for (int j = 0; j < 8; ++j)
                    acc[i][j] += a[i] * b[j];
        }
        __syncthreads();
    }

#pragma unroll
    for (int ig = 0; ig < 2; ++ig)
#pragma unroll
    for (int ii = 0; ii < 4; ++ii) {
        int r = row0 + ig * 64 + ty * 4 + ii;
        if (r >= M) continue;
#pragma unroll
        for (int jg = 0; jg < 2; ++jg) {
            int c = col0 + jg * 64 + tx * 4;
            if (c + 3 >= N) continue;
            float v[4];
#pragma unroll
            for (int q = 0; q < 4; ++q) {
                v[q] = acc[ig * 4 + ii][jg * 4 + q];
                if (HAS_BIAS) v[q] += bias[c + q];
                if (RELU)     v[q] = fmaxf(v[q], 0.f);
            }
            if (C_BF16) {
                ushort4 o;
                o.x = f2bf(v[0]); o.y = f2bf(v[1]);
                o.z = f2bf(v[2]); o.w = f2bf(v[3]);
                *(ushort4*)((unsigned short*)Cv + (size_t)r * N + c) = o;
            } else {
                float4 o = make_float4(v[0], v[1], v[2], v[3]);
                *(float4*)((float*)Cv + (size_t)r * N + c) = o;
            }
        }
    }
}

// ---------------------------------------------------------------------------
// dst[i,:] = sum_j src[nei[i,j], :]   (bf16 in/out, fp32 accumulate)
// one block per atom, 128 threads x 4 elements (ushort4)
// ---------------------------------------------------------------------------
__global__ __launch_bounds__(128)
void gather_kernel(const unsigned short* __restrict__ src,
                   const int* __restrict__ nei, unsigned short* __restrict__ dst)
{
    const int atom = blockIdx.x;
    const int d4   = threadIdx.x * 4;
    const int* np_ = nei + (size_t)atom * MAX_NEI;
    float a0 = 0.f, a1 = 0.f, a2 = 0.f, a3 = 0.f;
#pragma unroll
    for (int j = 0; j < MAX_NEI; ++j) {
        int idx = np_[j];
        ushort4 v = *(const ushort4*)(src + (size_t)idx * HIDDEN + d4);
        a0 += bf2f(v.x); a1 += bf2f(v.y); a2 += bf2f(v.z); a3 += bf2f(v.w);
    }
    ushort4 o;
    o.x = f2bf(a0); o.y = f2bf(a1); o.z = f2bf(a2); o.w = f2bf(a3);
    *(ushort4*)(dst + (size_t)atom * HIDDEN + d4) = o;
}

// ---------------------------------------------------------------------------
// segment-mean over sorted mol_ids: one block per molecule (binary search),
// 256 threads x 2 elements. Empty segment -> 0. bf16 in, fp32 out.
// ---------------------------------------------------------------------------
__global__ __launch_bounds__(256)
void segmean_kernel(const unsigned short* __restrict__ H,
                    const int* __restrict__ mol_ids, float* __restrict__ molv)
{
    const int m = blockIdx.x;
    const int d = threadIdx.x * 2;
    int lo = 0, hi = N_ATOMS;
    while (lo < hi) { int mid = (lo + hi) >> 1; if (mol_ids[mid] < m) lo = mid + 1; else hi = mid; }
    const int start = lo;
    hi = N_ATOMS;
    while (lo < hi) { int mid = (lo + hi) >> 1; if (mol_ids[mid] < m + 1) lo = mid + 1; else hi = mid; }
    const int end = lo;
    float s0 = 0.f, s1 = 0.f;
    for (int a = start; a < end; ++a) {
        ushort2 v = *(const ushort2*)(H + (size_t)a * HIDDEN + d);
        s0 += bf2f(v.x); s1 += bf2f(v.y);
    }
    int cnt = end - start;
    float inv = 1.0f / (float)(cnt > 0 ? cnt : 1);
    float2 o; o.x = s0 * inv; o.y = s1 * inv;
    *(float2*)(molv + (size_t)m * HIDDEN + d) = o;
}

// ---------------------------------------------------------------------------
// feature[p,:] = [e1+e2 | e1*e2 | e1 | e2]  (fp32)
// ---------------------------------------------------------------------------
__global__ __launch_bounds__(128)
void feature_kernel(const float* __restrict__ molv, const int* __restrict__ edges,
                    float* __restrict__ feat)
{
    const int p  = blockIdx.x;
    const int d4 = threadIdx.x * 4;
    const int i  = edges[p];
    const int j  = edges[N_PAIRS + p];
    float4 a = *(const float4*)(molv + (size_t)i * HIDDEN + d4);
    float4 b = *(const float4*)(molv + (size_t)j * HIDDEN + d4);
    float* o = feat + (size_t)p * (4 * HIDDEN);
    *(float4*)(o + d4)              = make_float4(a.x + b.x, a.y + b.y, a.z + b.z, a.w + b.w);
    *(float4*)(o + HIDDEN + d4)     = make_float4(a.x * b.x, a.y * b.y, a.z * b.z, a.w * b.w);
    *(float4*)(o + 2 * HIDDEN + d4) = a;
    *(float4*)(o + 3 * HIDDEN + d4) = b;
}

// ---------------------------------------------------------------------------
// out[p] = sigmoid(dot(H[p,:1024], w) + b)
// ---------------------------------------------------------------------------
__global__ __launch_bounds__(256)
void final_kernel(const float* __restrict__ H, const float* __restrict__ w,
                  const float* __restrict__ b, float* __restrict__ out)
{
    const int p   = blockIdx.x;
    const int tid = threadIdx.x;
    const float* row = H + (size_t)p * 1024;
    float s = 0.f;
    for (int i = tid; i < 1024; i += 256) s += row[i] * w[i];
#pragma unroll
    for (int off = 32; off > 0; off >>= 1) s += __shfl_down(s, off, 64);
    __shared__ float red[4];
    if ((tid & 63) == 0) red[tid >> 6] = s;
    __syncthreads();
    if (tid == 0) {
        float t = red[0] + red[1] + red[2] + red[3] + b[0];
        out[p] = 1.0f / (1.0f + expf(-t));
    }
}

// ---------------------------------------------------------------------------
// Workspace layout (peak 213.2 MB):
//   [0, 102.4 MB)          X : bf16 [N_ATOMS, 512]   (atom phase)
//   [102.4, 204.8 MB)      Y : bf16 [N_ATOMS, 512]   (atom phase)
//   [204.8, 213.2 MB)      Mv: fp32 [N_MOLS, 512]
//   ffn phase reuses [0, 204.8):
//     F  fp32 [8192,2048] @ 0        (67.1 MB)
//     H1 fp32 [8192,2048] @ 67.1 MB
//     H2 fp32 [8192,1024] @ 134.2 MB
// ---------------------------------------------------------------------------
extern "C" void kernel_launch(void* const* d_in, const int* in_sizes, int n_in,
                              void* d_out, int out_size, void* d_ws, size_t ws_size,
                              hipStream_t stream)
{
    const float* f_atoms = (const float*)d_in[0];
    const int*   a_nei   = (const int*)d_in[1];
    const int*   mol_ids = (const int*)d_in[2];
    const int*   edges   = (const int*)d_in[3];
    const float* W_i     = (const float*)d_in[4];
    const float* W_h     = (const float*)d_in[5];
    const float* W_o     = (const float*)d_in[6];
    const float* b_o     = (const float*)d_in[7];
    const float* W_ffn_i = (const float*)d_in[8];
    const float* b_ffn_i = (const float*)d_in[9];
    const float* W_ffn_1 = (const float*)d_in[10];
    const float* b_ffn_1 = (const float*)d_in[11];
    const float* W_ffn_2 = (const float*)d_in[12];
    const float* b_ffn_2 = (const float*)d_in[13];
    float* out = (float*)d_out;

    const size_t XSZ = (size_t)N_ATOMS * HIDDEN * sizeof(unsigned short); // 102.4 MB
    unsigned short* X  = (unsigned short*)d_ws;
    unsigned short* Y  = (unsigned short*)((char*)d_ws + XSZ);
    float*          Mv = (float*)((char*)d_ws + 2 * XSZ);
    float* F  = (float*)d_ws;
    float* H1 = (float*)((char*)d_ws + (size_t)N_PAIRS * 2048 * 4);
    float* H2 = (float*)((char*)d_ws + (size_t)N_PAIRS * 2048 * 8);

    dim3 blk(256);
    auto grid_for = [](int M, int N) { return dim3((N + 127) / 128, (M + 127) / 128); };

    // 1) X = relu(f_atoms @ W_i)                       [bf16]
    gemm2_kernel<true, false, false, true><<<grid_for(N_ATOMS, HIDDEN), blk, 0, stream>>>(
        f_atoms, nullptr, W_i, nullptr, nullptr, X, N_ATOMS, HIDDEN, ATOM_FDIM, 0);
    // 2) Y = gather-sum(X)
    gather_kernel<<<N_ATOMS, 128, 0, stream>>>(X, a_nei, Y);
    // 3) X = relu(f_atoms @ W_i + Y @ W_h)             [concat-K GEMM]
    gemm2_kernel<true, false, true, true><<<grid_for(N_ATOMS, HIDDEN), blk, 0, stream>>>(
        f_atoms, Y, W_i, W_h, nullptr, X, N_ATOMS, HIDDEN, ATOM_FDIM, HIDDEN);
    // 4) Y = gather-sum(X)
    gather_kernel<<<N_ATOMS, 128, 0, stream>>>(X, a_nei, Y);
    // 5) X = relu(f_atoms @ W_o[:133] + Y @ W_o[133:] + b_o)
    gemm2_kernel<true, true, true, true><<<grid_for(N_ATOMS, HIDDEN), blk, 0, stream>>>(
        f_atoms, Y, W_o, W_o + (size_t)ATOM_FDIM * HIDDEN, b_o, X,
        N_ATOMS, HIDDEN, ATOM_FDIM, HIDDEN);
    // 6) Mv = segment-mean(X)
    segmean_kernel<<<N_MOLS, 256, 0, stream>>>(X, mol_ids, Mv);
    // 7) F = [e1+e2|e1*e2|e1|e2]                       [fp32, overwrites X region]
    feature_kernel<<<N_PAIRS, 128, 0, stream>>>(Mv, edges, F);
    // 8) H1 = relu(F @ W_ffn_i + b_ffn_i)
    gemm2_kernel<true, true, false, false><<<grid_for(N_PAIRS, 2048), blk, 0, stream>>>(
        F, nullptr, W_ffn_i, nullptr, b_ffn_i, H1, N_PAIRS, 2048, 4 * HIDDEN, 0);
    // 9) H2 = relu(H1 @ W_ffn_1 + b_ffn_1)
    gemm2_kernel<true, true, false, false><<<grid_for(N_PAIRS, 1024), blk, 0, stream>>>(
        H1, nullptr, W_ffn_1, nullptr, b_ffn_1, H2, N_PAIRS, 1024, 2048, 0);
    // 10) out = sigmoid(H2 @ W_ffn_2 + b_ffn_2)
    final_kernel<<<N_PAIRS, 256, 0, stream>>>(H2, W_ffn_2, b_ffn_2, out);
    (void)in_sizes; (void)n_in; (void)out_size; (void)ws_size;
}

// Round 3
// 1681.588 us; speedup vs baseline: 3.6082x; 3.6082x over previous
//
#include <hip/hip_runtime.h>
#include <math.h>

#define N_ATOMS   100000
#define ATOM_FDIM 133
#define HIDDEN    512
#define MAX_NEI   6
#define N_MOLS    4096
#define N_PAIRS   8192

typedef __attribute__((ext_vector_type(8))) short short8;
typedef __attribute__((ext_vector_type(4))) float f32x4;

static __device__ __forceinline__ float bf2f(unsigned short h) {
    return __uint_as_float(((unsigned int)h) << 16);
}
static __device__ __forceinline__ unsigned short f2bf(float f) {
    unsigned int u = __float_as_uint(f);
    u += 0x7FFFu + ((u >> 16) & 1u);
    return (unsigned short)(u >> 16);
}
// pack two fp32 -> two bf16 in a uint (lo = a, hi = b), RNE
static __device__ __forceinline__ unsigned int pk2bf(float a, float b) {
    unsigned int ua = __float_as_uint(a); ua += 0x7FFFu + ((ua >> 16) & 1u);
    unsigned int ub = __float_as_uint(b); ub += 0x7FFFu + ((ub >> 16) & 1u);
    return (ua >> 16) | (ub & 0xFFFF0000u);
}

// ---------------------------------------------------------------------------
// MFMA bf16 GEMM: C(bf16) = act( A @ B [+bias] [+addm] )
//  A: bf16 [M, lda] (A_FP32: fp32 [M, lda], converted during staging)
//  B: fp32 [Kv, N] row-major, converted to bf16 during staging
//  Kp: padded K loop bound (multiple of 64, >= Kv); A bf16 path needs lda=Kp.
//  128x128 tile, BK=64, 256 thr = 4 waves, each wave 64x64 via 4x4 MFMA accs.
//  LDS: As[m][k] stride 72 (b128 frag reads, 2-way free);
//       Bs[k][n] stride 132 (u16 frag reads 2-way free; b64 writes 4-way).
// ---------------------------------------------------------------------------
template<bool A_FP32, bool RELU, bool HAS_BIAS, bool HAS_ADD>
__global__ __launch_bounds__(256)
void mfma_gemm(const void* __restrict__ Ap, int lda, int Kp, int Kv,
               const float* __restrict__ B, int N,
               const float* __restrict__ bias,
               const unsigned short* __restrict__ addm,
               unsigned short* __restrict__ C, int M)
{
    __shared__ unsigned short As[128 * 72];
    __shared__ unsigned short Bs[64 * 132];
    const int tid  = threadIdx.x;
    const int row0 = blockIdx.y * 128;
    const int col0 = blockIdx.x * 128;
    const int lane = tid & 63;
    const int wid  = tid >> 6;
    const int wm   = wid & 1, wn = wid >> 1;
    const int quad = lane >> 4, l15 = lane & 15;

    f32x4 acc[4][4];
#pragma unroll
    for (int i = 0; i < 4; ++i)
#pragma unroll
        for (int j = 0; j < 4; ++j)
#pragma unroll
            for (int r = 0; r < 4; ++r) acc[i][j][r] = 0.f;

    for (int k0 = 0; k0 < Kp; k0 += 64) {
        __syncthreads();
        // ---- stage A (128 rows x 64 k) -> As[m][k]
#pragma unroll
        for (int i = 0; i < 4; ++i) {
            int v = tid + i * 256;            // 0..1023
            int m = v >> 3, kc = (v & 7) * 8;
            int r = row0 + m;
            uint4 u;
            if (A_FP32) {
                const float* Af = (const float*)Ap;
                const float* Arow = Af + (size_t)r * lda;
                bool rok = (r < M);
                float f[8];
#pragma unroll
                for (int e = 0; e < 8; ++e) {
                    int gk = k0 + kc + e;
                    f[e] = (rok && gk < Kv) ? Arow[gk] : 0.f;
                }
                u.x = pk2bf(f[0], f[1]); u.y = pk2bf(f[2], f[3]);
                u.z = pk2bf(f[4], f[5]); u.w = pk2bf(f[6], f[7]);
            } else {
                const unsigned short* Ab = (const unsigned short*)Ap;
                u = make_uint4(0u, 0u, 0u, 0u);
                if (r < M) u = *(const uint4*)(Ab + (size_t)r * lda + k0 + kc);
            }
            *(uint4*)&As[m * 72 + kc] = u;
        }
        // ---- stage B (64 k x 128 n) fp32 -> bf16 -> Bs[k][n]
        {
            int n4 = (tid & 31) * 4;
            int kg = (tid >> 5) * 8;
#pragma unroll
            for (int dk = 0; dk < 8; ++dk) {
                int gk = k0 + kg + dk;
                float4 f = make_float4(0.f, 0.f, 0.f, 0.f);
                if (gk < Kv) f = *(const float4*)(B + (size_t)gk * N + col0 + n4);
                uint2 w;
                w.x = pk2bf(f.x, f.y); w.y = pk2bf(f.z, f.w);
                *(uint2*)&Bs[(kg + dk) * 132 + n4] = w;
            }
        }
        __syncthreads();
        // ---- compute: 2 k-steps of 32
#pragma unroll
        for (int ks = 0; ks < 2; ++ks) {
            int kb = ks * 32 + quad * 8;
            short8 a[4];
#pragma unroll
            for (int mt = 0; mt < 4; ++mt)
                a[mt] = *(const short8*)&As[(wm * 64 + mt * 16 + l15) * 72 + kb];
#pragma unroll
            for (int nt = 0; nt < 4; ++nt) {
                int nn = wn * 64 + nt * 16 + l15;
                short8 b;
#pragma unroll
                for (int j = 0; j < 8; ++j)
                    b[j] = (short)Bs[(kb + j) * 132 + nn];
#pragma unroll
                for (int mt = 0; mt < 4; ++mt)
                    acc[mt][nt] = __builtin_amdgcn_mfma_f32_16x16x32_bf16(
                        a[mt], b, acc[mt][nt], 0, 0, 0);
            }
        }
    }

    // ---- epilogue: C[m][n] with m = quad*4+r (C/D layout), n = lane&15
#pragma unroll
    for (int nt = 0; nt < 4; ++nt) {
        int n = col0 + wn * 64 + nt * 16 + l15;
        float bi = HAS_BIAS ? bias[n] : 0.f;
#pragma unroll
        for (int mt = 0; mt < 4; ++mt) {
            int mbase = row0 + wm * 64 + mt * 16 + quad * 4;
#pragma unroll
            for (int r = 0; r < 4; ++r) {
                int m = mbase + r;
                if (m < M) {
                    float v = acc[mt][nt][r] + bi;
                    if (HAS_ADD) v += bf2f(addm[(size_t)m * N + n]);
                    if (RELU)    v = fmaxf(v, 0.f);
                    C[(size_t)m * N + n] = f2bf(v);
                }
            }
        }
    }
}

// ---------------------------------------------------------------------------
// gather-sum: dst[a,:] = sum_j (RELU? relu:id)(src[nei[a,j],:])  (bf16)
// one wave per atom, lane handles 8 elements (uint4)
// ---------------------------------------------------------------------------
template<bool RELU>
__global__ __launch_bounds__(256)
void gather_kernel(const unsigned short* __restrict__ src,
                   const int* __restrict__ nei, unsigned short* __restrict__ dst)
{
    const int atom = blockIdx.x * 4 + (threadIdx.x >> 6);
    const int lane = threadIdx.x & 63;
    const int off  = lane * 8;
    const int* np_ = nei + (size_t)atom * MAX_NEI;
    float s[8];
#pragma unroll
    for (int e = 0; e < 8; ++e) s[e] = 0.f;
#pragma unroll
    for (int j = 0; j < MAX_NEI; ++j) {
        int idx = np_[j];
        uint4 u = *(const uint4*)(src + (size_t)idx * HIDDEN + off);
        unsigned int w[4] = {u.x, u.y, u.z, u.w};
#pragma unroll
        for (int q = 0; q < 4; ++q) {
            float lo = __uint_as_float(w[q] << 16);
            float hi = __uint_as_float(w[q] & 0xFFFF0000u);
            if (RELU) { lo = fmaxf(lo, 0.f); hi = fmaxf(hi, 0.f); }
            s[2 * q]     += lo;
            s[2 * q + 1] += hi;
        }
    }
    uint4 o;
    o.x = pk2bf(s[0], s[1]); o.y = pk2bf(s[2], s[3]);
    o.z = pk2bf(s[4], s[5]); o.w = pk2bf(s[6], s[7]);
    *(uint4*)(dst + (size_t)atom * HIDDEN + off) = o;
}

// ---------------------------------------------------------------------------
// segment-mean over sorted mol_ids (bf16 in, fp32 out). Empty -> 0.
// ---------------------------------------------------------------------------
__global__ __launch_bounds__(256)
void segmean_kernel(const unsigned short* __restrict__ H,
                    const int* __restrict__ mol_ids, float* __restrict__ molv)
{
    const int m = blockIdx.x;
    const int d = threadIdx.x * 2;
    int lo = 0, hi = N_ATOMS;
    while (lo < hi) { int mid = (lo + hi) >> 1; if (mol_ids[mid] < m) lo = mid + 1; else hi = mid; }
    const int start = lo;
    hi = N_ATOMS;
    while (lo < hi) { int mid = (lo + hi) >> 1; if (mol_ids[mid] < m + 1) lo = mid + 1; else hi = mid; }
    const int end = lo;
    float s0 = 0.f, s1 = 0.f;
    for (int a = start; a < end; ++a) {
        unsigned int u = *(const unsigned int*)(H + (size_t)a * HIDDEN + d);
        s0 += __uint_as_float(u << 16);
        s1 += __uint_as_float(u & 0xFFFF0000u);
    }
    int cnt = end - start;
    float inv = 1.0f / (float)(cnt > 0 ? cnt : 1);
    float2 o; o.x = s0 * inv; o.y = s1 * inv;
    *(float2*)(molv + (size_t)m * HIDDEN + d) = o;
}

// ---------------------------------------------------------------------------
// feature[p,:] = [e1+e2 | e1*e2 | e1 | e2]  (fp32 molv -> bf16 feature)
// ---------------------------------------------------------------------------
__global__ __launch_bounds__(128)
void feature_kernel(const float* __restrict__ molv, const int* __restrict__ edges,
                    unsigned short* __restrict__ feat)
{
    const int p  = blockIdx.x;
    const int d4 = threadIdx.x * 4;
    const int i  = edges[p];
    const int j  = edges[N_PAIRS + p];
    float4 a = *(const float4*)(molv + (size_t)i * HIDDEN + d4);
    float4 b = *(const float4*)(molv + (size_t)j * HIDDEN + d4);
    unsigned short* o = feat + (size_t)p * (4 * HIDDEN);
    uint2 w;
    w.x = pk2bf(a.x + b.x, a.y + b.y); w.y = pk2bf(a.z + b.z, a.w + b.w);
    *(uint2*)(o + d4) = w;
    w.x = pk2bf(a.x * b.x, a.y * b.y); w.y = pk2bf(a.z * b.z, a.w * b.w);
    *(uint2*)(o + HIDDEN + d4) = w;
    w.x = pk2bf(a.x, a.y); w.y = pk2bf(a.z, a.w);
    *(uint2*)(o + 2 * HIDDEN + d4) = w;
    w.x = pk2bf(b.x, b.y); w.y = pk2bf(b.z, b.w);
    *(uint2*)(o + 3 * HIDDEN + d4) = w;
}

// ---------------------------------------------------------------------------
// out[p] = sigmoid(dot(H2[p,:1024], w) + b)   (H2 bf16)
// ---------------------------------------------------------------------------
__global__ __launch_bounds__(256)
void final_kernel(const unsigned short* __restrict__ H, const float* __restrict__ w,
                  const float* __restrict__ b, float* __restrict__ out)
{
    const int p   = blockIdx.x;
    const int tid = threadIdx.x;
    const unsigned short* row = H + (size_t)p * 1024;
    float s = 0.f;
    for (int i = tid; i < 1024; i += 256) s += bf2f(row[i]) * w[i];
#pragma unroll
    for (int off = 32; off > 0; off >>= 1) s += __shfl_down(s, off, 64);
    __shared__ float red[4];
    if ((tid & 63) == 0) red[tid >> 6] = s;
    __syncthreads();
    if (tid == 0) {
        float t = red[0] + red[1] + red[2] + red[3] + b[0];
        out[p] = 1.0f / (1.0f + expf(-t));
    }
}

// ---------------------------------------------------------------------------
// Workspace (peak 204.8 MB):
//   I: bf16 [100000,512] @ 0          (102.4 MB)
//   Y: bf16 [100000,512] @ 102.4 MB   (102.4 MB)
//   Mv: fp32 [4096,512]  @ 102.4 MB   (reuses Y after step 5b)
//   FFN (reuses I region): F bf16 [8192,2048] @0, H1 bf16 @33.55MB,
//                          H2 bf16 [8192,1024] @67.1MB
// ---------------------------------------------------------------------------
extern "C" void kernel_launch(void* const* d_in, const int* in_sizes, int n_in,
                              void* d_out, int out_size, void* d_ws, size_t ws_size,
                              hipStream_t stream)
{
    const float* f_atoms = (const float*)d_in[0];
    const int*   a_nei   = (const int*)d_in[1];
    const int*   mol_ids = (const int*)d_in[2];
    const int*   edges   = (const int*)d_in[3];
    const float* W_i     = (const float*)d_in[4];
    const float* W_h     = (const float*)d_in[5];
    const float* W_o     = (const float*)d_in[6];
    const float* b_o     = (const float*)d_in[7];
    const float* W_ffn_i = (const float*)d_in[8];
    const float* b_ffn_i = (const float*)d_in[9];
    const float* W_ffn_1 = (const float*)d_in[10];
    const float* b_ffn_1 = (const float*)d_in[11];
    const float* W_ffn_2 = (const float*)d_in[12];
    const float* b_ffn_2 = (const float*)d_in[13];
    float* out = (float*)d_out;

    const size_t XSZ = (size_t)N_ATOMS * HIDDEN * sizeof(unsigned short); // 102.4 MB
    unsigned short* I  = (unsigned short*)d_ws;
    unsigned short* Y  = (unsigned short*)((char*)d_ws + XSZ);
    float*          Mv = (float*)((char*)d_ws + XSZ);                     // after Y dies
    unsigned short* F  = (unsigned short*)d_ws;
    unsigned short* H1 = (unsigned short*)((char*)d_ws + (size_t)N_PAIRS * 2048 * 2);
    unsigned short* H2 = (unsigned short*)((char*)d_ws + (size_t)N_PAIRS * 2048 * 4);

    const int MB_ATOM = (N_ATOMS + 127) / 128;   // 782
    const int MB_PAIR = N_PAIRS / 128;           // 64

    // 1) I = f_atoms @ W_i            (pre-relu "inp", bf16)
    mfma_gemm<true, false, false, false><<<dim3(4, MB_ATOM), 256, 0, stream>>>(
        f_atoms, ATOM_FDIM, 192, ATOM_FDIM, W_i, HIDDEN, nullptr, nullptr, I, N_ATOMS);
    // 2) Y = gather-sum(relu(I))
    gather_kernel<true><<<N_ATOMS / 4, 256, 0, stream>>>(I, a_nei, Y);
    // 3) I = relu(I + Y @ W_h)        (in-place add)
    mfma_gemm<false, true, false, true><<<dim3(4, MB_ATOM), 256, 0, stream>>>(
        Y, HIDDEN, HIDDEN, HIDDEN, W_h, HIDDEN, nullptr, I, I, N_ATOMS);
    // 4) Y = gather-sum(I)
    gather_kernel<false><<<N_ATOMS / 4, 256, 0, stream>>>(I, a_nei, Y);
    // 5a) I = f_atoms @ W_o[:133] + b_o
    mfma_gemm<true, false, true, false><<<dim3(4, MB_ATOM), 256, 0, stream>>>(
        f_atoms, ATOM_FDIM, 192, ATOM_FDIM, W_o, HIDDEN, b_o, nullptr, I, N_ATOMS);
    // 5b) I = relu(I + Y @ W_o[133:])
    mfma_gemm<false, true, false, true><<<dim3(4, MB_ATOM), 256, 0, stream>>>(
        Y, HIDDEN, HIDDEN, HIDDEN, W_o + (size_t)ATOM_FDIM * HIDDEN, HIDDEN,
        nullptr, I, I, N_ATOMS);
    // 6) Mv = segment-mean(I)         (Mv in Y region; Y dead)
    segmean_kernel<<<N_MOLS, 256, 0, stream>>>(I, mol_ids, Mv);
    // 7) F = [e1+e2|e1*e2|e1|e2]      (bf16, I region; I dead)
    feature_kernel<<<N_PAIRS, 128, 0, stream>>>(Mv, edges, F);
    // 8) H1 = relu(F @ W_ffn_i + b_ffn_i)
    mfma_gemm<false, true, true, false><<<dim3(16, MB_PAIR), 256, 0, stream>>>(
        F, 2048, 2048, 2048, W_ffn_i, 2048, b_ffn_i, nullptr, H1, N_PAIRS);
    // 9) H2 = relu(H1 @ W_ffn_1 + b_ffn_1)
    mfma_gemm<false, true, true, false><<<dim3(8, MB_PAIR), 256, 0, stream>>>(
        H1, 2048, 2048, 2048, W_ffn_1, 1024, b_ffn_1, nullptr, H2, N_PAIRS);
    // 10) out = sigmoid(H2 @ W_ffn_2 + b_ffn_2)
    final_kernel<<<N_PAIRS, 256, 0, stream>>>(H2, W_ffn_2, b_ffn_2, out);
    (void)in_sizes; (void)n_in; (void)out_size; (void)ws_size;
}

// Round 4
// 1135.422 us; speedup vs baseline: 5.3439x; 1.4810x over previous
//
#include <hip/hip_runtime.h>
#include <math.h>

#define N_ATOMS   100000
#define ATOM_FDIM 133
#define HIDDEN    512
#define MAX_NEI   6
#define N_MOLS    4096
#define N_PAIRS   8192

typedef __attribute__((ext_vector_type(8))) short short8;
typedef __attribute__((ext_vector_type(4))) float f32x4;

static __device__ __forceinline__ float bf2f(unsigned short h) {
    return __uint_as_float(((unsigned int)h) << 16);
}
static __device__ __forceinline__ unsigned short f2bf(float f) {
    unsigned int u = __float_as_uint(f);
    u += 0x7FFFu + ((u >> 16) & 1u);
    return (unsigned short)(u >> 16);
}
static __device__ __forceinline__ unsigned int pk2bf(float a, float b) {
    unsigned int ua = __float_as_uint(a); ua += 0x7FFFu + ((ua >> 16) & 1u);
    unsigned int ub = __float_as_uint(b); ub += 0x7FFFu + ((ub >> 16) & 1u);
    return (ua >> 16) | (ub & 0xFFFF0000u);
}

// async global->LDS, 16B per lane; LDS base must be wave-uniform
static __device__ __forceinline__ void gl_lds16(const void* g, void* l) {
    __builtin_amdgcn_global_load_lds(
        (__attribute__((address_space(1))) void*)g,
        (__attribute__((address_space(3))) void*)l, 16, 0, 0);
}

// ---------------------------------------------------------------------------
// m97-style MFMA GEMM: C(bf16[M,N]) = act( A @ Bt^T [+bias] [+addm] )
//   A : bf16 [M, lda] (A_FP32: fp32 [M, lda], converted during staging)
//   Bt: bf16 [N, Kp]  (transposed weights, zero-padded to Kp)
//   Kp: K loop bound (multiple of 64). bf16-A path needs lda == Kp and
//       tolerates OOB row reads (rows >= M feed discarded C rows only).
// 128x128 tile, BK=64, 256 thr = 4 waves (2x2), 4x4 accs of 16x16x32.
// LDS: As[128][64], Bs[128][64] bf16, unpadded (global_load_lds layout);
// all fragment reads are ds_read_b128 (K-contiguous).
// ---------------------------------------------------------------------------
template<bool A_FP32, bool RELU, bool HAS_BIAS, bool HAS_ADD>
__global__ __launch_bounds__(256)
void gemm_bt(const void* __restrict__ Ap, int lda, int Kp, int Kv,
             const unsigned short* __restrict__ Bt,
             const float* __restrict__ bias,
             const unsigned short* __restrict__ addm,
             unsigned short* __restrict__ C, int M, int N)
{
    __shared__ unsigned short As[128 * 64];
    __shared__ unsigned short Bs[128 * 64];
    const int tid  = threadIdx.x;
    const int lane = tid & 63;
    const int wid  = tid >> 6;
    const int row0 = blockIdx.y * 128;
    const int col0 = blockIdx.x * 128;
    const int wm   = wid & 1, wn = wid >> 1;
    const int quad = lane >> 4, l15 = lane & 15;
    const int srow = lane >> 3;          // 0..7   staging row within 8-row slab
    const int scol = (lane & 7) * 8;     // 0..56  staging k-offset (8 bf16 = 16B)

    f32x4 acc[4][4];
#pragma unroll
    for (int i = 0; i < 4; ++i)
#pragma unroll
        for (int j = 0; j < 4; ++j)
#pragma unroll
            for (int r = 0; r < 4; ++r) acc[i][j][r] = 0.f;

    for (int k0 = 0; k0 < Kp; k0 += 64) {
        __syncthreads();
        if (A_FP32) {
            const float* Af = (const float*)Ap;
#pragma unroll
            for (int i = 0; i < 4; ++i) {
                int v = tid + i * 256;           // 0..1023
                int m = v >> 3, kc = (v & 7) * 8;
                int r = row0 + m;
                const float* Arow = Af + (size_t)r * lda;
                bool rok = (r < M);
                float f[8];
#pragma unroll
                for (int e = 0; e < 8; ++e) {
                    int gk = k0 + kc + e;
                    f[e] = (rok && gk < Kv) ? Arow[gk] : 0.f;
                }
                uint4 u;
                u.x = pk2bf(f[0], f[1]); u.y = pk2bf(f[2], f[3]);
                u.z = pk2bf(f[4], f[5]); u.w = pk2bf(f[6], f[7]);
                *(uint4*)&As[m * 64 + kc] = u;
            }
        } else {
            const unsigned short* Ab = (const unsigned short*)Ap;
#pragma unroll
            for (int i = 0; i < 4; ++i) {
                int mbase = wid * 32 + i * 8;    // wave-uniform
                int r = row0 + mbase + srow;     // per-lane global row
                gl_lds16(Ab + (size_t)r * lda + k0 + scol, &As[mbase * 64]);
            }
        }
#pragma unroll
        for (int i = 0; i < 4; ++i) {
            int nbase = wid * 32 + i * 8;        // wave-uniform
            int rn = col0 + nbase + srow;        // N is a multiple of 128
            gl_lds16(Bt + (size_t)rn * Kp + k0 + scol, &Bs[nbase * 64]);
        }
        __syncthreads();
#pragma unroll
        for (int ks = 0; ks < 2; ++ks) {
            int kb = ks * 32 + quad * 8;
            short8 a[4], b[4];
#pragma unroll
            for (int mt = 0; mt < 4; ++mt)
                a[mt] = *(const short8*)&As[(wm * 64 + mt * 16 + l15) * 64 + kb];
#pragma unroll
            for (int nt = 0; nt < 4; ++nt)
                b[nt] = *(const short8*)&Bs[(wn * 64 + nt * 16 + l15) * 64 + kb];
#pragma unroll
            for (int mt = 0; mt < 4; ++mt)
#pragma unroll
                for (int nt = 0; nt < 4; ++nt)
                    acc[mt][nt] = __builtin_amdgcn_mfma_f32_16x16x32_bf16(
                        a[mt], b[nt], acc[mt][nt], 0, 0, 0);
        }
    }

    // epilogue: C row = quad*4 + r (C/D layout), col = l15  [verified R3]
#pragma unroll
    for (int nt = 0; nt < 4; ++nt) {
        int n = col0 + wn * 64 + nt * 16 + l15;
        float bi = HAS_BIAS ? bias[n] : 0.f;
#pragma unroll
        for (int mt = 0; mt < 4; ++mt) {
            int mbase = row0 + wm * 64 + mt * 16 + quad * 4;
#pragma unroll
            for (int r = 0; r < 4; ++r) {
                int m = mbase + r;
                if (m < M) {
                    float v = acc[mt][nt][r] + bi;
                    if (HAS_ADD) v += bf2f(addm[(size_t)m * N + n]);
                    if (RELU)    v = fmaxf(v, 0.f);
                    C[(size_t)m * N + n] = f2bf(v);
                }
            }
        }
    }
}

// ---------------------------------------------------------------------------
// transpose + fp32->bf16: out[n][k] = in[k][n], zero-pad k in [K, Kp)
// ---------------------------------------------------------------------------
__global__ __launch_bounds__(256)
void transpose_bf16(const float* __restrict__ in, int K, int N,
                    unsigned short* __restrict__ out, int Kp)
{
    __shared__ float t[32][33];
    const int n0 = blockIdx.x * 32, k0 = blockIdx.y * 32;
    const int tx = threadIdx.x & 31, ty = threadIdx.x >> 5;   // 32 x 8
#pragma unroll
    for (int i = 0; i < 32; i += 8) {
        int k = k0 + ty + i, n = n0 + tx;
        t[ty + i][tx] = (k < K && n < N) ? in[(size_t)k * N + n] : 0.f;
    }
    __syncthreads();
#pragma unroll
    for (int i = 0; i < 32; i += 8) {
        int n = n0 + ty + i, k = k0 + tx;
        if (n < N && k < Kp)
            out[(size_t)n * Kp + k] = f2bf(t[tx][ty + i]);
    }
}

// ---------------------------------------------------------------------------
// gather-sum: dst[a,:] = sum_j (RELU? relu:id)(src[nei[a,j],:])  (bf16)
// ---------------------------------------------------------------------------
template<bool RELU>
__global__ __launch_bounds__(256)
void gather_kernel(const unsigned short* __restrict__ src,
                   const int* __restrict__ nei, unsigned short* __restrict__ dst)
{
    const int atom = blockIdx.x * 4 + (threadIdx.x >> 6);
    const int lane = threadIdx.x & 63;
    const int off  = lane * 8;
    const int* np_ = nei + (size_t)atom * MAX_NEI;
    float s[8];
#pragma unroll
    for (int e = 0; e < 8; ++e) s[e] = 0.f;
#pragma unroll
    for (int j = 0; j < MAX_NEI; ++j) {
        int idx = np_[j];
        uint4 u = *(const uint4*)(src + (size_t)idx * HIDDEN + off);
        unsigned int w[4] = {u.x, u.y, u.z, u.w};
#pragma unroll
        for (int q = 0; q < 4; ++q) {
            float lo = __uint_as_float(w[q] << 16);
            float hi = __uint_as_float(w[q] & 0xFFFF0000u);
            if (RELU) { lo = fmaxf(lo, 0.f); hi = fmaxf(hi, 0.f); }
            s[2 * q]     += lo;
            s[2 * q + 1] += hi;
        }
    }
    uint4 o;
    o.x = pk2bf(s[0], s[1]); o.y = pk2bf(s[2], s[3]);
    o.z = pk2bf(s[4], s[5]); o.w = pk2bf(s[6], s[7]);
    *(uint4*)(dst + (size_t)atom * HIDDEN + off) = o;
}

// ---------------------------------------------------------------------------
__global__ __launch_bounds__(256)
void segmean_kernel(const unsigned short* __restrict__ H,
                    const int* __restrict__ mol_ids, float* __restrict__ molv)
{
    const int m = blockIdx.x;
    const int d = threadIdx.x * 2;
    int lo = 0, hi = N_ATOMS;
    while (lo < hi) { int mid = (lo + hi) >> 1; if (mol_ids[mid] < m) lo = mid + 1; else hi = mid; }
    const int start = lo;
    hi = N_ATOMS;
    while (lo < hi) { int mid = (lo + hi) >> 1; if (mol_ids[mid] < m + 1) lo = mid + 1; else hi = mid; }
    const int end = lo;
    float s0 = 0.f, s1 = 0.f;
    for (int a = start; a < end; ++a) {
        unsigned int u = *(const unsigned int*)(H + (size_t)a * HIDDEN + d);
        s0 += __uint_as_float(u << 16);
        s1 += __uint_as_float(u & 0xFFFF0000u);
    }
    int cnt = end - start;
    float inv = 1.0f / (float)(cnt > 0 ? cnt : 1);
    float2 o; o.x = s0 * inv; o.y = s1 * inv;
    *(float2*)(molv + (size_t)m * HIDDEN + d) = o;
}

// ---------------------------------------------------------------------------
__global__ __launch_bounds__(128)
void feature_kernel(const float* __restrict__ molv, const int* __restrict__ edges,
                    unsigned short* __restrict__ feat)
{
    const int p  = blockIdx.x;
    const int d4 = threadIdx.x * 4;
    const int i  = edges[p];
    const int j  = edges[N_PAIRS + p];
    float4 a = *(const float4*)(molv + (size_t)i * HIDDEN + d4);
    float4 b = *(const float4*)(molv + (size_t)j * HIDDEN + d4);
    unsigned short* o = feat + (size_t)p * (4 * HIDDEN);
    uint2 w;
    w.x = pk2bf(a.x + b.x, a.y + b.y); w.y = pk2bf(a.z + b.z, a.w + b.w);
    *(uint2*)(o + d4) = w;
    w.x = pk2bf(a.x * b.x, a.y * b.y); w.y = pk2bf(a.z * b.z, a.w * b.w);
    *(uint2*)(o + HIDDEN + d4) = w;
    w.x = pk2bf(a.x, a.y); w.y = pk2bf(a.z, a.w);
    *(uint2*)(o + 2 * HIDDEN + d4) = w;
    w.x = pk2bf(b.x, b.y); w.y = pk2bf(b.z, b.w);
    *(uint2*)(o + 3 * HIDDEN + d4) = w;
}

// ---------------------------------------------------------------------------
__global__ __launch_bounds__(256)
void final_kernel(const unsigned short* __restrict__ H, const float* __restrict__ w,
                  const float* __restrict__ b, float* __restrict__ out)
{
    const int p   = blockIdx.x;
    const int tid = threadIdx.x;
    const unsigned short* row = H + (size_t)p * 1024;
    float s = 0.f;
    for (int i = tid; i < 1024; i += 256) s += bf2f(row[i]) * w[i];
#pragma unroll
    for (int off = 32; off > 0; off >>= 1) s += __shfl_down(s, off, 64);
    __shared__ float red[4];
    if ((tid & 63) == 0) red[tid >> 6] = s;
    __syncthreads();
    if (tid == 0) {
        float t = red[0] + red[1] + red[2] + red[3] + b[0];
        out[p] = 1.0f / (1.0f + expf(-t));
    }
}

// ---------------------------------------------------------------------------
// Workspace (peak 206.2 MB < proven-safe 213.2 MB):
//   I       bf16 [100000,512] @ 0
//   Y       bf16 [100000,512] @ 102,400,000
//   Wt_i    bf16 [512,192]    @ 204,800,000   (small weights: 1.45 MB)
//   Wt_o1   bf16 [512,192]
//   Wt_h    bf16 [512,512]
//   Wt_o2   bf16 [512,512]    -> ends 206,241,792
//   after step 5b (Y dead):  Mv fp32 [4096,512] @ Y+0,
//     Wt_ffn_i bf16 [2048,2048] @ Y+16 MB, Wt_ffn_1 bf16 [1024,2048] after it
//   after step 6 (I dead):   F/H1/H2 bf16 in I region
// ---------------------------------------------------------------------------
extern "C" void kernel_launch(void* const* d_in, const int* in_sizes, int n_in,
                              void* d_out, int out_size, void* d_ws, size_t ws_size,
                              hipStream_t stream)
{
    const float* f_atoms = (const float*)d_in[0];
    const int*   a_nei   = (const int*)d_in[1];
    const int*   mol_ids = (const int*)d_in[2];
    const int*   edges   = (const int*)d_in[3];
    const float* W_i     = (const float*)d_in[4];
    const float* W_h     = (const float*)d_in[5];
    const float* W_o     = (const float*)d_in[6];
    const float* b_o     = (const float*)d_in[7];
    const float* W_ffn_i = (const float*)d_in[8];
    const float* b_ffn_i = (const float*)d_in[9];
    const float* W_ffn_1 = (const float*)d_in[10];
    const float* b_ffn_1 = (const float*)d_in[11];
    const float* W_ffn_2 = (const float*)d_in[12];
    const float* b_ffn_2 = (const float*)d_in[13];
    float* out = (float*)d_out;

    char* ws = (char*)d_ws;
    unsigned short* I     = (unsigned short*)ws;
    unsigned short* Y     = (unsigned short*)(ws + 102400000);
    unsigned short* Wt_i  = (unsigned short*)(ws + 204800000);
    unsigned short* Wt_o1 = Wt_i  + 512 * 192;
    unsigned short* Wt_h  = Wt_o1 + 512 * 192;
    unsigned short* Wt_o2 = Wt_h  + 512 * 512;
    float*          Mv    = (float*)(ws + 102400000);
    unsigned short* Wt_f0 = (unsigned short*)(ws + 102400000 + 16777216);
    unsigned short* Wt_f1 = Wt_f0 + (size_t)2048 * 2048;
    unsigned short* F     = (unsigned short*)ws;
    unsigned short* H1    = F  + (size_t)N_PAIRS * 2048;
    unsigned short* H2    = H1 + (size_t)N_PAIRS * 2048;

    const int MB_ATOM = (N_ATOMS + 127) / 128;   // 782

    // --- weight prep (small weights; FFN weights transposed later) ---
    transpose_bf16<<<dim3(16, 6),  256, 0, stream>>>(W_i, ATOM_FDIM, HIDDEN, Wt_i, 192);
    transpose_bf16<<<dim3(16, 6),  256, 0, stream>>>(W_o, ATOM_FDIM, HIDDEN, Wt_o1, 192);
    transpose_bf16<<<dim3(16, 16), 256, 0, stream>>>(W_h, HIDDEN, HIDDEN, Wt_h, HIDDEN);
    transpose_bf16<<<dim3(16, 16), 256, 0, stream>>>(W_o + (size_t)ATOM_FDIM * HIDDEN,
                                                     HIDDEN, HIDDEN, Wt_o2, HIDDEN);

    // 1) I = f_atoms @ W_i   (pre-relu inp)
    gemm_bt<true, false, false, false><<<dim3(4, MB_ATOM), 256, 0, stream>>>(
        f_atoms, ATOM_FDIM, 192, ATOM_FDIM, Wt_i, nullptr, nullptr, I, N_ATOMS, HIDDEN);
    // 2) Y = gather-sum(relu(I))
    gather_kernel<true><<<N_ATOMS / 4, 256, 0, stream>>>(I, a_nei, Y);
    // 3) I = relu(I + Y @ W_h)
    gemm_bt<false, true, false, true><<<dim3(4, MB_ATOM), 256, 0, stream>>>(
        Y, HIDDEN, HIDDEN, HIDDEN, Wt_h, nullptr, I, I, N_ATOMS, HIDDEN);
    // 4) Y = gather-sum(I)
    gather_kernel<false><<<N_ATOMS / 4, 256, 0, stream>>>(I, a_nei, Y);
    // 5a) I = f_atoms @ W_o[:133] + b_o
    gemm_bt<true, false, true, false><<<dim3(4, MB_ATOM), 256, 0, stream>>>(
        f_atoms, ATOM_FDIM, 192, ATOM_FDIM, Wt_o1, b_o, nullptr, I, N_ATOMS, HIDDEN);
    // 5b) I = relu(I + Y @ W_o[133:])
    gemm_bt<false, true, false, true><<<dim3(4, MB_ATOM), 256, 0, stream>>>(
        Y, HIDDEN, HIDDEN, HIDDEN, Wt_o2, nullptr, I, I, N_ATOMS, HIDDEN);
    // 6) Mv = segment-mean(I)            (Y region; Y dead)
    segmean_kernel<<<N_MOLS, 256, 0, stream>>>(I, mol_ids, Mv);
    // FFN weight prep (Y region after Mv)
    transpose_bf16<<<dim3(64, 64), 256, 0, stream>>>(W_ffn_i, 2048, 2048, Wt_f0, 2048);
    transpose_bf16<<<dim3(32, 64), 256, 0, stream>>>(W_ffn_1, 2048, 1024, Wt_f1, 2048);
    // 7) F = [e1+e2|e1*e2|e1|e2]         (I region; I dead)
    feature_kernel<<<N_PAIRS, 128, 0, stream>>>(Mv, edges, F);
    // 8) H1 = relu(F @ W_ffn_i + b_ffn_i)
    gemm_bt<false, true, true, false><<<dim3(16, N_PAIRS / 128), 256, 0, stream>>>(
        F, 2048, 2048, 2048, Wt_f0, b_ffn_i, nullptr, H1, N_PAIRS, 2048);
    // 9) H2 = relu(H1 @ W_ffn_1 + b_ffn_1)
    gemm_bt<false, true, true, false><<<dim3(8, N_PAIRS / 128), 256, 0, stream>>>(
        H1, 2048, 2048, 2048, Wt_f1, b_ffn_1, nullptr, H2, N_PAIRS, 1024);
    // 10) out = sigmoid(H2 @ W_ffn_2 + b_ffn_2)
    final_kernel<<<N_PAIRS, 256, 0, stream>>>(H2, W_ffn_2, b_ffn_2, out);
    (void)in_sizes; (void)n_in; (void)out_size; (void)ws_size;
}

// Round 5
// 931.656 us; speedup vs baseline: 6.5127x; 1.2187x over previous
//
#include <hip/hip_runtime.h>
#include <math.h>

#define N_ATOMS   100000
#define ATOM_FDIM 133
#define HIDDEN    512
#define MAX_NEI   6
#define N_MOLS    4096
#define N_PAIRS   8192

typedef __attribute__((ext_vector_type(8))) short short8;
typedef __attribute__((ext_vector_type(4))) float f32x4;

static __device__ __forceinline__ float bf2f(unsigned short h) {
    return __uint_as_float(((unsigned int)h) << 16);
}
static __device__ __forceinline__ unsigned short f2bf(float f) {
    unsigned int u = __float_as_uint(f);
    u += 0x7FFFu + ((u >> 16) & 1u);
    return (unsigned short)(u >> 16);
}
static __device__ __forceinline__ unsigned int pk2bf(float a, float b) {
    unsigned int ua = __float_as_uint(a); ua += 0x7FFFu + ((ua >> 16) & 1u);
    unsigned int ub = __float_as_uint(b); ub += 0x7FFFu + ((ub >> 16) & 1u);
    return (ua >> 16) | (ub & 0xFFFF0000u);
}
static __device__ __forceinline__ void gl_lds16(const void* g, void* l) {
    __builtin_amdgcn_global_load_lds(
        (__attribute__((address_space(1))) void*)g,
        (__attribute__((address_space(3))) void*)l, 16, 0, 0);
}

// ---------------------------------------------------------------------------
// Concat-K MFMA GEMM:  C(bf16[M,N]) = act( [A1_f32 | A2_bf16] @ Bt^T [+bias] )
//   A1: fp32 [M, Kv1] (rows guarded, k zero-padded to K1p)
//   A2: bf16 [M, lda2] (global_load_lds staging; OOB rows must be ws-safe)
//   Bt: bf16 [N, Kp] transposed weights (zero-padded), Kp = K1p + K2
// 128x128 tile, BK=64, 4 waves, 4x4 accs of 16x16x32.
// Epilogue: accs -> LDS bf16 tile Ct[128][136] -> coalesced uint4 stores.
// SWZ: same-row-block tiles mapped to one XCD (L2 A-reuse); needs gridY%8==0.
// ---------------------------------------------------------------------------
template<bool HAS_A1, bool HAS_A2, bool RELU, bool HAS_BIAS, bool SWZ>
__global__ __launch_bounds__(256)
void gemm_bt(const float* __restrict__ A1, int Kv1, int K1p,
             const unsigned short* __restrict__ A2, int lda2, int Kp,
             const unsigned short* __restrict__ Bt,
             const float* __restrict__ bias,
             unsigned short* __restrict__ C, int M, int N)
{
    __shared__ unsigned short lds[128 * 136];        // 34.8 KB
    unsigned short* As = lds;                        // [128][64]
    unsigned short* Bs = lds + 128 * 64;             // [128][64]
    unsigned short* Ct = lds;                        // [128][136] (epilogue)

    const int tid  = threadIdx.x;
    const int lane = tid & 63;
    const int wid  = tid >> 6;
    int bx, by;
    if (SWZ) {
        int L = blockIdx.y * gridDim.x + blockIdx.x;
        int xcd = L & 7, s = L >> 3;
        bx = s % gridDim.x;
        by = xcd + 8 * (s / gridDim.x);
    } else { bx = blockIdx.x; by = blockIdx.y; }
    const int row0 = by * 128;
    const int col0 = bx * 128;
    const int wm   = wid & 1, wn = wid >> 1;
    const int quad = lane >> 4, l15 = lane & 15;
    const int srow = lane >> 3;
    const int scol = (lane & 7) * 8;

    f32x4 acc[4][4];
#pragma unroll
    for (int i = 0; i < 4; ++i)
#pragma unroll
        for (int j = 0; j < 4; ++j)
#pragma unroll
            for (int r = 0; r < 4; ++r) acc[i][j][r] = 0.f;

    for (int k0 = 0; k0 < Kp; k0 += 64) {
        __syncthreads();
        if (HAS_A1 && k0 < K1p) {
            // fp32 -> bf16 convert staging (guarded)
            bool kfull = (k0 + 63 < Kv1);
#pragma unroll
            for (int i = 0; i < 4; ++i) {
                int v = tid + i * 256;
                int m = v >> 3, kc = (v & 7) * 8;
                int r = row0 + m;
                const float* Arow = A1 + (size_t)r * Kv1;
                bool rok = (r < M);
                float f[8];
                if (kfull) {
#pragma unroll
                    for (int e = 0; e < 8; ++e) f[e] = rok ? Arow[k0 + kc + e] : 0.f;
                } else {
#pragma unroll
                    for (int e = 0; e < 8; ++e) {
                        int gk = k0 + kc + e;
                        f[e] = (rok && gk < Kv1) ? Arow[gk] : 0.f;
                    }
                }
                uint4 u;
                u.x = pk2bf(f[0], f[1]); u.y = pk2bf(f[2], f[3]);
                u.z = pk2bf(f[4], f[5]); u.w = pk2bf(f[6], f[7]);
                *(uint4*)&As[m * 64 + kc] = u;
            }
        } else if (HAS_A2) {
            int kof = HAS_A1 ? (k0 - K1p) : k0;
#pragma unroll
            for (int i = 0; i < 4; ++i) {
                int mbase = wid * 32 + i * 8;                 // wave-uniform
                int r = row0 + mbase + srow;
                gl_lds16(A2 + (size_t)r * lda2 + kof + scol, &As[mbase * 64]);
            }
        }
#pragma unroll
        for (int i = 0; i < 4; ++i) {
            int nbase = wid * 32 + i * 8;                     // wave-uniform
            int rn = col0 + nbase + srow;
            gl_lds16(Bt + (size_t)rn * Kp + k0 + scol, &Bs[nbase * 64]);
        }
        __syncthreads();
#pragma unroll
        for (int ks = 0; ks < 2; ++ks) {
            int kb = ks * 32 + quad * 8;
            short8 a[4], b[4];
#pragma unroll
            for (int mt = 0; mt < 4; ++mt)
                a[mt] = *(const short8*)&As[(wm * 64 + mt * 16 + l15) * 64 + kb];
#pragma unroll
            for (int nt = 0; nt < 4; ++nt)
                b[nt] = *(const short8*)&Bs[(wn * 64 + nt * 16 + l15) * 64 + kb];
#pragma unroll
            for (int mt = 0; mt < 4; ++mt)
#pragma unroll
                for (int nt = 0; nt < 4; ++nt)
                    acc[mt][nt] = __builtin_amdgcn_mfma_f32_16x16x32_bf16(
                        a[mt], b[nt], acc[mt][nt], 0, 0, 0);
        }
    }

    // ---- epilogue: accs -> Ct (bf16, stride 136) -> coalesced stores
    __syncthreads();
#pragma unroll
    for (int mt = 0; mt < 4; ++mt)
#pragma unroll
        for (int nt = 0; nt < 4; ++nt) {
            int cbase = wn * 64 + nt * 16 + l15;
            int rbase = wm * 64 + mt * 16 + quad * 4;
#pragma unroll
            for (int r = 0; r < 4; ++r)
                Ct[(rbase + r) * 136 + cbase] = f2bf(acc[mt][nt][r]);
        }
    __syncthreads();
#pragma unroll
    for (int i = 0; i < 8; ++i) {
        int c = tid + i * 256;                 // 0..2047
        int rr = c >> 4, cc = (c & 15) * 8;
        int m = row0 + rr, n = col0 + cc;
        short8 v = *(const short8*)&Ct[rr * 136 + cc];
        float f[8];
#pragma unroll
        for (int q = 0; q < 8; ++q) f[q] = bf2f((unsigned short)v[q]);
        if (HAS_BIAS) {
            float4 b0 = *(const float4*)(bias + n);
            float4 b1 = *(const float4*)(bias + n + 4);
            f[0] += b0.x; f[1] += b0.y; f[2] += b0.z; f[3] += b0.w;
            f[4] += b1.x; f[5] += b1.y; f[6] += b1.z; f[7] += b1.w;
        }
        if (RELU)
#pragma unroll
            for (int q = 0; q < 8; ++q) f[q] = fmaxf(f[q], 0.f);
        if (m < M) {
            uint4 o;
            o.x = pk2bf(f[0], f[1]); o.y = pk2bf(f[2], f[3]);
            o.z = pk2bf(f[4], f[5]); o.w = pk2bf(f[6], f[7]);
            *(uint4*)(C + (size_t)m * N + n) = o;
        }
    }
}

// ---------------------------------------------------------------------------
// transpose + fp32->bf16: out[n*ldOut + k] = in[k][n]; zero for k in [K,Kpad)
// ---------------------------------------------------------------------------
__global__ __launch_bounds__(256)
void transpose_bf16(const float* __restrict__ in, int K, int N,
                    unsigned short* __restrict__ out, int ldOut, int Kpad)
{
    __shared__ float t[32][33];
    const int n0 = blockIdx.x * 32, k0 = blockIdx.y * 32;
    const int tx = threadIdx.x & 31, ty = threadIdx.x >> 5;
#pragma unroll
    for (int i = 0; i < 32; i += 8) {
        int k = k0 + ty + i, n = n0 + tx;
        t[ty + i][tx] = (k < K && n < N) ? in[(size_t)k * N + n] : 0.f;
    }
    __syncthreads();
#pragma unroll
    for (int i = 0; i < 32; i += 8) {
        int n = n0 + ty + i, k = k0 + tx;
        if (n < N && k < Kpad)
            out[(size_t)n * ldOut + k] = f2bf(t[tx][ty + i]);
    }
}

// ---------------------------------------------------------------------------
template<bool RELU>
__global__ __launch_bounds__(256)
void gather_kernel(const unsigned short* __restrict__ src,
                   const int* __restrict__ nei, unsigned short* __restrict__ dst)
{
    const int atom = blockIdx.x * 4 + (threadIdx.x >> 6);
    const int lane = threadIdx.x & 63;
    const int off  = lane * 8;
    const int* np_ = nei + (size_t)atom * MAX_NEI;
    float s[8];
#pragma unroll
    for (int e = 0; e < 8; ++e) s[e] = 0.f;
#pragma unroll
    for (int j = 0; j < MAX_NEI; ++j) {
        int idx = np_[j];
        uint4 u = *(const uint4*)(src + (size_t)idx * HIDDEN + off);
        unsigned int w[4] = {u.x, u.y, u.z, u.w};
#pragma unroll
        for (int q = 0; q < 4; ++q) {
            float lo = __uint_as_float(w[q] << 16);
            float hi = __uint_as_float(w[q] & 0xFFFF0000u);
            if (RELU) { lo = fmaxf(lo, 0.f); hi = fmaxf(hi, 0.f); }
            s[2 * q]     += lo;
            s[2 * q + 1] += hi;
        }
    }
    uint4 o;
    o.x = pk2bf(s[0], s[1]); o.y = pk2bf(s[2], s[3]);
    o.z = pk2bf(s[4], s[5]); o.w = pk2bf(s[6], s[7]);
    *(uint4*)(dst + (size_t)atom * HIDDEN + off) = o;
}

// ---------------------------------------------------------------------------
__global__ __launch_bounds__(256)
void segmean_kernel(const unsigned short* __restrict__ H,
                    const int* __restrict__ mol_ids, float* __restrict__ molv)
{
    const int m = blockIdx.x;
    const int d = threadIdx.x * 2;
    int lo = 0, hi = N_ATOMS;
    while (lo < hi) { int mid = (lo + hi) >> 1; if (mol_ids[mid] < m) lo = mid + 1; else hi = mid; }
    const int start = lo;
    hi = N_ATOMS;
    while (lo < hi) { int mid = (lo + hi) >> 1; if (mol_ids[mid] < m + 1) lo = mid + 1; else hi = mid; }
    const int end = lo;
    float s0 = 0.f, s1 = 0.f;
    for (int a = start; a < end; ++a) {
        unsigned int u = *(const unsigned int*)(H + (size_t)a * HIDDEN + d);
        s0 += __uint_as_float(u << 16);
        s1 += __uint_as_float(u & 0xFFFF0000u);
    }
    int cnt = end - start;
    float inv = 1.0f / (float)(cnt > 0 ? cnt : 1);
    float2 o; o.x = s0 * inv; o.y = s1 * inv;
    *(float2*)(molv + (size_t)m * HIDDEN + d) = o;
}

// ---------------------------------------------------------------------------
__global__ __launch_bounds__(128)
void feature_kernel(const float* __restrict__ molv, const int* __restrict__ edges,
                    unsigned short* __restrict__ feat)
{
    const int p  = blockIdx.x;
    const int d4 = threadIdx.x * 4;
    const int i  = edges[p];
    const int j  = edges[N_PAIRS + p];
    float4 a = *(const float4*)(molv + (size_t)i * HIDDEN + d4);
    float4 b = *(const float4*)(molv + (size_t)j * HIDDEN + d4);
    unsigned short* o = feat + (size_t)p * (4 * HIDDEN);
    uint2 w;
    w.x = pk2bf(a.x + b.x, a.y + b.y); w.y = pk2bf(a.z + b.z, a.w + b.w);
    *(uint2*)(o + d4) = w;
    w.x = pk2bf(a.x * b.x, a.y * b.y); w.y = pk2bf(a.z * b.z, a.w * b.w);
    *(uint2*)(o + HIDDEN + d4) = w;
    w.x = pk2bf(a.x, a.y); w.y = pk2bf(a.z, a.w);
    *(uint2*)(o + 2 * HIDDEN + d4) = w;
    w.x = pk2bf(b.x, b.y); w.y = pk2bf(b.z, b.w);
    *(uint2*)(o + 3 * HIDDEN + d4) = w;
}

// ---------------------------------------------------------------------------
__global__ __launch_bounds__(256)
void final_kernel(const unsigned short* __restrict__ H, const float* __restrict__ w,
                  const float* __restrict__ b, float* __restrict__ out)
{
    const int p   = blockIdx.x;
    const int tid = threadIdx.x;
    const unsigned short* row = H + (size_t)p * 1024;
    float s = 0.f;
    for (int i = tid; i < 1024; i += 256) s += bf2f(row[i]) * w[i];
#pragma unroll
    for (int off = 32; off > 0; off >>= 1) s += __shfl_down(s, off, 64);
    __shared__ float red[4];
    if ((tid & 63) == 0) red[tid >> 6] = s;
    __syncthreads();
    if (tid == 0) {
        float t = red[0] + red[1] + red[2] + red[3] + b[0];
        out[p] = 1.0f / (1.0f + expf(-t));
    }
}

// ---------------------------------------------------------------------------
// Workspace (peak 206.44 MB < proven-safe 213.2 MB):
//   I    bf16 [100000,512] @ 0
//   Y    bf16 [100000,512] @ 102,400,000
//   Wt_i bf16 [512,192]    @ 204,800,000
//   Wch  bf16 [512,704]    @ 204,996,608   ([W_i|W_h] rows)
//   Wco  bf16 [512,704]    @ 205,717,504   ([W_o1|W_o2] rows) ends 206,438,400
//   after Y dies: Mv fp32 [4096,512] @ Y, Wt_f0 @ Y+16MB, Wt_f1 after
//   after I dies: F/H1/H2 bf16 in I region
// OOB note: padded 784-row grids read A2 rows up to 100351 -> at most
// Y+102.76 MB = ws offset 205.2 MB, inside allocated ws (garbage, discarded).
// ---------------------------------------------------------------------------
extern "C" void kernel_launch(void* const* d_in, const int* in_sizes, int n_in,
                              void* d_out, int out_size, void* d_ws, size_t ws_size,
                              hipStream_t stream)
{
    const float* f_atoms = (const float*)d_in[0];
    const int*   a_nei   = (const int*)d_in[1];
    const int*   mol_ids = (const int*)d_in[2];
    const int*   edges   = (const int*)d_in[3];
    const float* W_i     = (const float*)d_in[4];
    const float* W_h     = (const float*)d_in[5];
    const float* W_o     = (const float*)d_in[6];
    const float* b_o     = (const float*)d_in[7];
    const float* W_ffn_i = (const float*)d_in[8];
    const float* b_ffn_i = (const float*)d_in[9];
    const float* W_ffn_1 = (const float*)d_in[10];
    const float* b_ffn_1 = (const float*)d_in[11];
    const float* W_ffn_2 = (const float*)d_in[12];
    const float* b_ffn_2 = (const float*)d_in[13];
    float* out = (float*)d_out;

    char* ws = (char*)d_ws;
    unsigned short* I     = (unsigned short*)ws;
    unsigned short* Y     = (unsigned short*)(ws + 102400000);
    unsigned short* Wt_i  = (unsigned short*)(ws + 204800000);
    unsigned short* Wch   = Wt_i + 512 * 192;
    unsigned short* Wco   = Wch  + 512 * 704;
    float*          Mv    = (float*)(ws + 102400000);
    unsigned short* Wt_f0 = (unsigned short*)(ws + 102400000 + 16777216);
    unsigned short* Wt_f1 = Wt_f0 + (size_t)2048 * 2048;
    unsigned short* F     = (unsigned short*)ws;
    unsigned short* H1    = F  + (size_t)N_PAIRS * 2048;
    unsigned short* H2    = H1 + (size_t)N_PAIRS * 2048;

    // --- weight prep (atom-phase weights) ---
    transpose_bf16<<<dim3(16, 6),  256, 0, stream>>>(W_i, 133, 512, Wt_i, 192, 192);
    transpose_bf16<<<dim3(16, 6),  256, 0, stream>>>(W_i, 133, 512, Wch, 704, 192);
    transpose_bf16<<<dim3(16, 16), 256, 0, stream>>>(W_h, 512, 512, Wch + 192, 704, 512);
    transpose_bf16<<<dim3(16, 6),  256, 0, stream>>>(W_o, 133, 512, Wco, 704, 192);
    transpose_bf16<<<dim3(16, 16), 256, 0, stream>>>(W_o + (size_t)133 * 512,
                                                     512, 512, Wco + 192, 704, 512);

    // 1) I = f_atoms @ W_i   (pre-relu inp)
    gemm_bt<true, false, false, false, true><<<dim3(4, 784), 256, 0, stream>>>(
        f_atoms, 133, 192, nullptr, 0, 192, Wt_i, nullptr, I, N_ATOMS, HIDDEN);
    // 2) Y = gather-sum(relu(I))
    gather_kernel<true><<<N_ATOMS / 4, 256, 0, stream>>>(I, a_nei, Y);
    // 3) I = relu([f_atoms | Y] @ [W_i ; W_h])   (concat-K, K=704)
    gemm_bt<true, true, true, false, true><<<dim3(4, 784), 256, 0, stream>>>(
        f_atoms, 133, 192, Y, 512, 704, Wch, nullptr, I, N_ATOMS, HIDDEN);
    // 4) Y = gather-sum(I)
    gather_kernel<false><<<N_ATOMS / 4, 256, 0, stream>>>(I, a_nei, Y);
    // 5) I = relu([f_atoms | Y] @ [W_o1 ; W_o2] + b_o)   (concat-K, K=704)
    gemm_bt<true, true, true, true, true><<<dim3(4, 784), 256, 0, stream>>>(
        f_atoms, 133, 192, Y, 512, 704, Wco, b_o, I, N_ATOMS, HIDDEN);
    // 6) Mv = segment-mean(I)            (Y region; Y dead)
    segmean_kernel<<<N_MOLS, 256, 0, stream>>>(I, mol_ids, Mv);
    // FFN weight prep (old-Y region, after Mv)
    transpose_bf16<<<dim3(64, 64), 256, 0, stream>>>(W_ffn_i, 2048, 2048, Wt_f0, 2048, 2048);
    transpose_bf16<<<dim3(32, 64), 256, 0, stream>>>(W_ffn_1, 2048, 1024, Wt_f1, 2048, 2048);
    // 7) F = [e1+e2|e1*e2|e1|e2]         (I region; I dead)
    feature_kernel<<<N_PAIRS, 128, 0, stream>>>(Mv, edges, F);
    // 8) H1 = relu(F @ W_ffn_i + b_ffn_i)
    gemm_bt<false, true, true, true, true><<<dim3(16, 64), 256, 0, stream>>>(
        nullptr, 0, 0, F, 2048, 2048, Wt_f0, b_ffn_i, H1, N_PAIRS, 2048);
    // 9) H2 = relu(H1 @ W_ffn_1 + b_ffn_1)
    gemm_bt<false, true, true, true, true><<<dim3(8, 64), 256, 0, stream>>>(
        nullptr, 0, 0, H1, 2048, 2048, Wt_f1, b_ffn_1, H2, N_PAIRS, 1024);
    // 10) out = sigmoid(H2 @ W_ffn_2 + b_ffn_2)
    final_kernel<<<N_PAIRS, 256, 0, stream>>>(H2, W_ffn_2, b_ffn_2, out);
    (void)in_sizes; (void)n_in; (void)out_size; (void)ws_size;
}

// Round 6
// 871.415 us; speedup vs baseline: 6.9629x; 1.0691x over previous
//
#include <hip/hip_runtime.h>
#include <math.h>

#define N_ATOMS   100000
#define ATOM_FDIM 133
#define HIDDEN    512
#define MAX_NEI   6
#define N_MOLS    4096
#define N_PAIRS   8192

typedef __attribute__((ext_vector_type(8))) short short8;
typedef __attribute__((ext_vector_type(4))) float f32x4;

static __device__ __forceinline__ float bf2f(unsigned short h) {
    return __uint_as_float(((unsigned int)h) << 16);
}
static __device__ __forceinline__ unsigned short f2bf(float f) {
    unsigned int u = __float_as_uint(f);
    u += 0x7FFFu + ((u >> 16) & 1u);
    return (unsigned short)(u >> 16);
}
static __device__ __forceinline__ unsigned int pk2bf(float a, float b) {
    unsigned int ua = __float_as_uint(a); ua += 0x7FFFu + ((ua >> 16) & 1u);
    unsigned int ub = __float_as_uint(b); ub += 0x7FFFu + ((ub >> 16) & 1u);
    return (ua >> 16) | (ub & 0xFFFF0000u);
}
static __device__ __forceinline__ void gl_lds16(const void* g, void* l) {
    __builtin_amdgcn_global_load_lds(
        (__attribute__((address_space(1))) void*)g,
        (__attribute__((address_space(3))) void*)l, 16, 0, 0);
}

// ---------------------------------------------------------------------------
// Concat-K MFMA GEMM:
//   C(bf16[M,N]) = act( [A1_f32 | A2_bf16] @ Bt^T [+bias] [+addm] )
//   A1: fp32 [M, Kv1] guarded, zero-padded to K1p; A2: bf16 [M, lda2]
//   Bt: bf16 [N, Kp] transposed weights, Kp = K1p + K2 (A2 k-extent)
// 128x128 tile, BK=64, 4 waves, 4x4 accs of 16x16x32.
// Epilogue: accs -> bf16 LDS tile Ct[128][128] (overlaps As+Bs; LDS=32KB
// exactly -> 5 blocks/CU) -> coalesced uint4 stores; bias/addm read there.
// In-place C==addm safe (each (m,n) read once by its writing thread).
// SWZ: same-row-block tiles on one XCD (L2 A-reuse); needs gridY%8==0.
// ---------------------------------------------------------------------------
template<bool HAS_A1, bool HAS_A2, bool RELU, bool HAS_BIAS, bool HAS_ADD, bool SWZ>
__global__ __launch_bounds__(256)
void gemm_bt(const float* __restrict__ A1, int Kv1, int K1p,
             const unsigned short* __restrict__ A2, int lda2, int Kp,
             const unsigned short* __restrict__ Bt,
             const float* __restrict__ bias,
             const unsigned short* __restrict__ addm,
             unsigned short* __restrict__ C, int M, int N)
{
    __shared__ unsigned short lds[128 * 128];        // 32768 B exactly
    unsigned short* As = lds;                        // [128][64]
    unsigned short* Bs = lds + 128 * 64;             // [128][64]
    unsigned short* Ct = lds;                        // [128][128] (epilogue)

    const int tid  = threadIdx.x;
    const int lane = tid & 63;
    const int wid  = tid >> 6;
    int bx, by;
    if (SWZ) {
        int L = blockIdx.y * gridDim.x + blockIdx.x;
        int xcd = L & 7, s = L >> 3;
        bx = s % gridDim.x;
        by = xcd + 8 * (s / gridDim.x);
    } else { bx = blockIdx.x; by = blockIdx.y; }
    const int row0 = by * 128;
    const int col0 = bx * 128;
    const int wm   = wid & 1, wn = wid >> 1;
    const int quad = lane >> 4, l15 = lane & 15;
    const int srow = lane >> 3;
    const int scol = (lane & 7) * 8;

    f32x4 acc[4][4];
#pragma unroll
    for (int i = 0; i < 4; ++i)
#pragma unroll
        for (int j = 0; j < 4; ++j)
#pragma unroll
            for (int r = 0; r < 4; ++r) acc[i][j][r] = 0.f;

    for (int k0 = 0; k0 < Kp; k0 += 64) {
        __syncthreads();
        if (HAS_A1 && k0 < K1p) {
            bool kfull = (k0 + 63 < Kv1);
#pragma unroll
            for (int i = 0; i < 4; ++i) {
                int v = tid + i * 256;
                int m = v >> 3, kc = (v & 7) * 8;
                int r = row0 + m;
                const float* Arow = A1 + (size_t)r * Kv1;
                bool rok = (r < M);
                float f[8];
                if (kfull) {
#pragma unroll
                    for (int e = 0; e < 8; ++e) f[e] = rok ? Arow[k0 + kc + e] : 0.f;
                } else {
#pragma unroll
                    for (int e = 0; e < 8; ++e) {
                        int gk = k0 + kc + e;
                        f[e] = (rok && gk < Kv1) ? Arow[gk] : 0.f;
                    }
                }
                uint4 u;
                u.x = pk2bf(f[0], f[1]); u.y = pk2bf(f[2], f[3]);
                u.z = pk2bf(f[4], f[5]); u.w = pk2bf(f[6], f[7]);
                *(uint4*)&As[m * 64 + kc] = u;
            }
        } else if (HAS_A2) {
            int kof = HAS_A1 ? (k0 - K1p) : k0;
#pragma unroll
            for (int i = 0; i < 4; ++i) {
                int mbase = wid * 32 + i * 8;                 // wave-uniform
                int r = row0 + mbase + srow;
                gl_lds16(A2 + (size_t)r * lda2 + kof + scol, &As[mbase * 64]);
            }
        }
#pragma unroll
        for (int i = 0; i < 4; ++i) {
            int nbase = wid * 32 + i * 8;                     // wave-uniform
            int rn = col0 + nbase + srow;
            gl_lds16(Bt + (size_t)rn * Kp + k0 + scol, &Bs[nbase * 64]);
        }
        __syncthreads();
#pragma unroll
        for (int ks = 0; ks < 2; ++ks) {
            int kb = ks * 32 + quad * 8;
            short8 a[4], b[4];
#pragma unroll
            for (int mt = 0; mt < 4; ++mt)
                a[mt] = *(const short8*)&As[(wm * 64 + mt * 16 + l15) * 64 + kb];
#pragma unroll
            for (int nt = 0; nt < 4; ++nt)
                b[nt] = *(const short8*)&Bs[(wn * 64 + nt * 16 + l15) * 64 + kb];
#pragma unroll
            for (int mt = 0; mt < 4; ++mt)
#pragma unroll
                for (int nt = 0; nt < 4; ++nt)
                    acc[mt][nt] = __builtin_amdgcn_mfma_f32_16x16x32_bf16(
                        a[mt], b[nt], acc[mt][nt], 0, 0, 0);
        }
    }

    // ---- epilogue: accs -> Ct[128][128] -> coalesced stores
    __syncthreads();
#pragma unroll
    for (int mt = 0; mt < 4; ++mt)
#pragma unroll
        for (int nt = 0; nt < 4; ++nt) {
            int cbase = wn * 64 + nt * 16 + l15;
            int rbase = wm * 64 + mt * 16 + quad * 4;
#pragma unroll
            for (int r = 0; r < 4; ++r)
                Ct[(rbase + r) * 128 + cbase] = f2bf(acc[mt][nt][r]);
        }
    __syncthreads();
#pragma unroll
    for (int i = 0; i < 8; ++i) {
        int c = tid + i * 256;                 // 0..2047
        int rr = c >> 4, cc = (c & 15) * 8;
        int m = row0 + rr, n = col0 + cc;
        short8 v = *(const short8*)&Ct[rr * 128 + cc];
        float f[8];
#pragma unroll
        for (int q = 0; q < 8; ++q) f[q] = bf2f((unsigned short)v[q]);
        if (HAS_BIAS) {
            float4 b0 = *(const float4*)(bias + n);
            float4 b1 = *(const float4*)(bias + n + 4);
            f[0] += b0.x; f[1] += b0.y; f[2] += b0.z; f[3] += b0.w;
            f[4] += b1.x; f[5] += b1.y; f[6] += b1.z; f[7] += b1.w;
        }
        if (m < M) {
            if (HAS_ADD) {
                uint4 ad = *(const uint4*)(addm + (size_t)m * N + n);
                unsigned int aw[4] = {ad.x, ad.y, ad.z, ad.w};
#pragma unroll
                for (int q = 0; q < 4; ++q) {
                    f[2 * q]     += __uint_as_float(aw[q] << 16);
                    f[2 * q + 1] += __uint_as_float(aw[q] & 0xFFFF0000u);
                }
            }
            if (RELU)
#pragma unroll
                for (int q = 0; q < 8; ++q) f[q] = fmaxf(f[q], 0.f);
            uint4 o;
            o.x = pk2bf(f[0], f[1]); o.y = pk2bf(f[2], f[3]);
            o.z = pk2bf(f[4], f[5]); o.w = pk2bf(f[6], f[7]);
            *(uint4*)(C + (size_t)m * N + n) = o;
        }
    }
}

// ---------------------------------------------------------------------------
// transpose + fp32->bf16: out[n*ldOut + koff + k] = in[k][n] (k in [0,Kz) of
// source; zero for k in [K, Kz))
// ---------------------------------------------------------------------------
__global__ __launch_bounds__(256)
void transpose_bf16(const float* __restrict__ in, int K, int N,
                    unsigned short* __restrict__ out, int ldOut, int Kz, int koff)
{
    __shared__ float t[32][33];
    const int n0 = blockIdx.x * 32, k0 = blockIdx.y * 32;
    const int tx = threadIdx.x & 31, ty = threadIdx.x >> 5;
#pragma unroll
    for (int i = 0; i < 32; i += 8) {
        int k = k0 + ty + i, n = n0 + tx;
        t[ty + i][tx] = (k < K && n < N) ? in[(size_t)k * N + n] : 0.f;
    }
    __syncthreads();
#pragma unroll
    for (int i = 0; i < 32; i += 8) {
        int n = n0 + ty + i, k = k0 + tx;
        if (n < N && k < Kz)
            out[(size_t)n * ldOut + koff + k] = f2bf(t[tx][ty + i]);
    }
}

// transpose of (A + B): out[n*ldOut + koff + k] = bf16(A[k][n] + B[k][n])
__global__ __launch_bounds__(256)
void transpose_add_bf16(const float* __restrict__ inA, const float* __restrict__ inB,
                        int K, int N, unsigned short* __restrict__ out,
                        int ldOut, int koff)
{
    __shared__ float t[32][33];
    const int n0 = blockIdx.x * 32, k0 = blockIdx.y * 32;
    const int tx = threadIdx.x & 31, ty = threadIdx.x >> 5;
#pragma unroll
    for (int i = 0; i < 32; i += 8) {
        int k = k0 + ty + i, n = n0 + tx;
        float v = 0.f;
        if (k < K && n < N) {
            v = inA[(size_t)k * N + n];
            if (inB) v += inB[(size_t)k * N + n];
        }
        t[ty + i][tx] = v;
    }
    __syncthreads();
#pragma unroll
    for (int i = 0; i < 32; i += 8) {
        int n = n0 + ty + i, k = k0 + tx;
        if (n < N && k < K)
            out[(size_t)n * ldOut + koff + k] = f2bf(t[tx][ty + i]);
    }
}

// ---------------------------------------------------------------------------
template<bool RELU>
__global__ __launch_bounds__(256)
void gather_kernel(const unsigned short* __restrict__ src,
                   const int* __restrict__ nei, unsigned short* __restrict__ dst)
{
    const int atom = blockIdx.x * 4 + (threadIdx.x >> 6);
    const int lane = threadIdx.x & 63;
    const int off  = lane * 8;
    const int* np_ = nei + (size_t)atom * MAX_NEI;
    float s[8];
#pragma unroll
    for (int e = 0; e < 8; ++e) s[e] = 0.f;
#pragma unroll
    for (int j = 0; j < MAX_NEI; ++j) {
        int idx = np_[j];
        uint4 u = *(const uint4*)(src + (size_t)idx * HIDDEN + off);
        unsigned int w[4] = {u.x, u.y, u.z, u.w};
#pragma unroll
        for (int q = 0; q < 4; ++q) {
            float lo = __uint_as_float(w[q] << 16);
            float hi = __uint_as_float(w[q] & 0xFFFF0000u);
            if (RELU) { lo = fmaxf(lo, 0.f); hi = fmaxf(hi, 0.f); }
            s[2 * q]     += lo;
            s[2 * q + 1] += hi;
        }
    }
    uint4 o;
    o.x = pk2bf(s[0], s[1]); o.y = pk2bf(s[2], s[3]);
    o.z = pk2bf(s[4], s[5]); o.w = pk2bf(s[6], s[7]);
    *(uint4*)(dst + (size_t)atom * HIDDEN + off) = o;
}

// ---------------------------------------------------------------------------
__global__ __launch_bounds__(256)
void segmean_kernel(const unsigned short* __restrict__ H,
                    const int* __restrict__ mol_ids, float* __restrict__ molv)
{
    const int m = blockIdx.x;
    const int d = threadIdx.x * 2;
    int lo = 0, hi = N_ATOMS;
    while (lo < hi) { int mid = (lo + hi) >> 1; if (mol_ids[mid] < m) lo = mid + 1; else hi = mid; }
    const int start = lo;
    hi = N_ATOMS;
    while (lo < hi) { int mid = (lo + hi) >> 1; if (mol_ids[mid] < m + 1) lo = mid + 1; else hi = mid; }
    const int end = lo;
    float s0 = 0.f, s1 = 0.f;
    for (int a = start; a < end; ++a) {
        unsigned int u = *(const unsigned int*)(H + (size_t)a * HIDDEN + d);
        s0 += __uint_as_float(u << 16);
        s1 += __uint_as_float(u & 0xFFFF0000u);
    }
    int cnt = end - start;
    float inv = 1.0f / (float)(cnt > 0 ? cnt : 1);
    float2 o; o.x = s0 * inv; o.y = s1 * inv;
    *(float2*)(molv + (size_t)m * HIDDEN + d) = o;
}

// ---------------------------------------------------------------------------
// feature[p,:] = [e1 | e2 | e1*e2]  (K=1536; matches [W0+W2; W0+W3; W1])
// ---------------------------------------------------------------------------
__global__ __launch_bounds__(128)
void feature_kernel(const float* __restrict__ molv, const int* __restrict__ edges,
                    unsigned short* __restrict__ feat)
{
    const int p  = blockIdx.x;
    const int d4 = threadIdx.x * 4;
    const int i  = edges[p];
    const int j  = edges[N_PAIRS + p];
    float4 a = *(const float4*)(molv + (size_t)i * HIDDEN + d4);
    float4 b = *(const float4*)(molv + (size_t)j * HIDDEN + d4);
    unsigned short* o = feat + (size_t)p * 1536;
    uint2 w;
    w.x = pk2bf(a.x, a.y); w.y = pk2bf(a.z, a.w);
    *(uint2*)(o + d4) = w;
    w.x = pk2bf(b.x, b.y); w.y = pk2bf(b.z, b.w);
    *(uint2*)(o + HIDDEN + d4) = w;
    w.x = pk2bf(a.x * b.x, a.y * b.y); w.y = pk2bf(a.z * b.z, a.w * b.w);
    *(uint2*)(o + 2 * HIDDEN + d4) = w;
}

// ---------------------------------------------------------------------------
__global__ __launch_bounds__(256)
void final_kernel(const unsigned short* __restrict__ H, const float* __restrict__ w,
                  const float* __restrict__ b, float* __restrict__ out)
{
    const int p   = blockIdx.x;
    const int tid = threadIdx.x;
    const unsigned short* row = H + (size_t)p * 1024;
    float s = 0.f;
    for (int i = tid; i < 1024; i += 256) s += bf2f(row[i]) * w[i];
#pragma unroll
    for (int off = 32; off > 0; off >>= 1) s += __shfl_down(s, off, 64);
    __shared__ float red[4];
    if ((tid & 63) == 0) red[tid >> 6] = s;
    __syncthreads();
    if (tid == 0) {
        float t = red[0] + red[1] + red[2] + red[3] + b[0];
        out[p] = 1.0f / (1.0f + expf(-t));
    }
}

// ---------------------------------------------------------------------------
// Workspace (peak 206.44 MB < proven-safe 213.2 MB):
//   I    bf16 [100000,512] @ 0
//   Y    bf16 [100000,512] @ 102,400,000
//   Wt_i bf16 [512,192]    @ 204,800,000
//   Wch  bf16 [512,512]    @ 204,996,608   (W_h^T; step 3 K=512)
//   Wco  bf16 [512,704]    @ 205,520,896   ([W_o1|W_o2]^T) ends ~206.24 MB
//   after Y dies: Mv fp32 [4096,512] @ Y; Wt_f0 bf16 [2048,1536] @ Y+16MB;
//                 Wt_f1 bf16 [1024,2048] after it
//   after I dies: F bf16[8192,1536] / H1[8192,2048] / H2[8192,1024] in I region
// OOB note: padded 784-row grids read A2/addm rows < 100352 -> Y+102.76 MB =
// ws offset 205.2 MB, inside allocated ws (garbage, discarded; addm guarded).
// ---------------------------------------------------------------------------
extern "C" void kernel_launch(void* const* d_in, const int* in_sizes, int n_in,
                              void* d_out, int out_size, void* d_ws, size_t ws_size,
                              hipStream_t stream)
{
    const float* f_atoms = (const float*)d_in[0];
    const int*   a_nei   = (const int*)d_in[1];
    const int*   mol_ids = (const int*)d_in[2];
    const int*   edges   = (const int*)d_in[3];
    const float* W_i     = (const float*)d_in[4];
    const float* W_h     = (const float*)d_in[5];
    const float* W_o     = (const float*)d_in[6];
    const float* b_o     = (const float*)d_in[7];
    const float* W_ffn_i = (const float*)d_in[8];
    const float* b_ffn_i = (const float*)d_in[9];
    const float* W_ffn_1 = (const float*)d_in[10];
    const float* b_ffn_1 = (const float*)d_in[11];
    const float* W_ffn_2 = (const float*)d_in[12];
    const float* b_ffn_2 = (const float*)d_in[13];
    float* out = (float*)d_out;

    char* ws = (char*)d_ws;
    unsigned short* I     = (unsigned short*)ws;
    unsigned short* Y     = (unsigned short*)(ws + 102400000);
    unsigned short* Wt_i  = (unsigned short*)(ws + 204800000);
    unsigned short* Wch   = Wt_i + 512 * 192;
    unsigned short* Wco   = Wch  + 512 * 512;
    float*          Mv    = (float*)(ws + 102400000);
    unsigned short* Wt_f0 = (unsigned short*)(ws + 102400000 + 16777216);
    unsigned short* Wt_f1 = Wt_f0 + (size_t)2048 * 1536;
    unsigned short* F     = (unsigned short*)ws;
    unsigned short* H1    = F  + (size_t)N_PAIRS * 1536;
    unsigned short* H2    = H1 + (size_t)N_PAIRS * 2048;

    const float* W0 = W_ffn_i;
    const float* W1 = W_ffn_i + (size_t)512 * 2048;
    const float* W2 = W_ffn_i + (size_t)1024 * 2048;
    const float* W3 = W_ffn_i + (size_t)1536 * 2048;

    // --- weight prep (atom-phase) ---
    transpose_bf16<<<dim3(16, 6),  256, 0, stream>>>(W_i, 133, 512, Wt_i, 192, 192, 0);
    transpose_bf16<<<dim3(16, 16), 256, 0, stream>>>(W_h, 512, 512, Wch, 512, 512, 0);
    transpose_bf16<<<dim3(16, 6),  256, 0, stream>>>(W_o, 133, 512, Wco, 704, 192, 0);
    transpose_bf16<<<dim3(16, 16), 256, 0, stream>>>(W_o + (size_t)133 * 512,
                                                     512, 512, Wco, 704, 512, 192);

    // 1) I = f_atoms @ W_i   (pre-relu inp; also addm for step 3)
    gemm_bt<true, false, false, false, false, true><<<dim3(4, 784), 256, 0, stream>>>(
        f_atoms, 133, 192, nullptr, 0, 192, Wt_i, nullptr, nullptr, I, N_ATOMS, HIDDEN);
    // 2) Y = gather-sum(relu(I))
    gather_kernel<true><<<N_ATOMS / 4, 256, 0, stream>>>(I, a_nei, Y);
    // 3) I = relu(I + Y @ W_h)     (in-place addm, K=512)
    gemm_bt<false, true, true, false, true, true><<<dim3(4, 784), 256, 0, stream>>>(
        nullptr, 0, 0, Y, 512, 512, Wch, nullptr, I, I, N_ATOMS, HIDDEN);
    // 4) Y = gather-sum(I)
    gather_kernel<false><<<N_ATOMS / 4, 256, 0, stream>>>(I, a_nei, Y);
    // 5) I = relu([f_atoms | Y] @ [W_o1 ; W_o2] + b_o)   (concat-K, K=704)
    gemm_bt<true, true, true, true, false, true><<<dim3(4, 784), 256, 0, stream>>>(
        f_atoms, 133, 192, Y, 512, 704, Wco, b_o, nullptr, I, N_ATOMS, HIDDEN);
    // 6) Mv = segment-mean(I)            (Y region; Y dead)
    segmean_kernel<<<N_MOLS, 256, 0, stream>>>(I, mol_ids, Mv);
    // FFN weight prep: Wt_f0 = [(W0+W2); (W0+W3); W1]^T  [2048 x 1536]
    transpose_add_bf16<<<dim3(64, 16), 256, 0, stream>>>(W0, W2, 512, 2048, Wt_f0, 1536, 0);
    transpose_add_bf16<<<dim3(64, 16), 256, 0, stream>>>(W0, W3, 512, 2048, Wt_f0, 1536, 512);
    transpose_add_bf16<<<dim3(64, 16), 256, 0, stream>>>(W1, nullptr, 512, 2048, Wt_f0, 1536, 1024);
    transpose_bf16<<<dim3(32, 64), 256, 0, stream>>>(W_ffn_1, 2048, 1024, Wt_f1, 2048, 2048, 0);
    // 7) F = [e1 | e2 | e1*e2]           (I region; I dead)
    feature_kernel<<<N_PAIRS, 128, 0, stream>>>(Mv, edges, F);
    // 8) H1 = relu(F @ Wt_f0^T + b_ffn_i)   (K=1536)
    gemm_bt<false, true, true, true, false, true><<<dim3(16, 64), 256, 0, stream>>>(
        nullptr, 0, 0, F, 1536, 1536, Wt_f0, b_ffn_i, nullptr, H1, N_PAIRS, 2048);
    // 9) H2 = relu(H1 @ W_ffn_1 + b_ffn_1)  (K=2048)
    gemm_bt<false, true, true, true, false, true><<<dim3(8, 64), 256, 0, stream>>>(
        nullptr, 0, 0, H1, 2048, 2048, Wt_f1, b_ffn_1, nullptr, H2, N_PAIRS, 1024);
    // 10) out = sigmoid(H2 @ W_ffn_2 + b_ffn_2)
    final_kernel<<<N_PAIRS, 256, 0, stream>>>(H2, W_ffn_2, b_ffn_2, out);
    (void)in_sizes; (void)n_in; (void)out_size; (void)ws_size;
}

// Round 7
// 806.379 us; speedup vs baseline: 7.5245x; 1.0807x over previous
//
#include <hip/hip_runtime.h>
#include <math.h>

#define N_ATOMS   100000
#define ATOM_FDIM 133
#define HIDDEN    512
#define MAX_NEI   6
#define N_MOLS    4096
#define N_PAIRS   8192

typedef __attribute__((ext_vector_type(8))) short short8;
typedef __attribute__((ext_vector_type(4))) float f32x4;

static __device__ __forceinline__ float bf2f(unsigned short h) {
    return __uint_as_float(((unsigned int)h) << 16);
}
static __device__ __forceinline__ unsigned short f2bf(float f) {
    unsigned int u = __float_as_uint(f);
    u += 0x7FFFu + ((u >> 16) & 1u);
    return (unsigned short)(u >> 16);
}
static __device__ __forceinline__ unsigned int pk2bf(float a, float b) {
    unsigned int ua = __float_as_uint(a); ua += 0x7FFFu + ((ua >> 16) & 1u);
    unsigned int ub = __float_as_uint(b); ub += 0x7FFFu + ((ub >> 16) & 1u);
    return (ua >> 16) | (ub & 0xFFFF0000u);
}
static __device__ __forceinline__ void gl_lds16(const void* g, void* l) {
    __builtin_amdgcn_global_load_lds(
        (__attribute__((address_space(1))) void*)g,
        (__attribute__((address_space(3))) void*)l, 16, 0, 0);
}

// ---------------------------------------------------------------------------
// Concat-K MFMA GEMM:
//   C(bf16[M,N]) = act( [A1_f32 | A2_bf16] @ Bt^T [+bias] [+addm] )
//   A1: fp32 [M, Kv1] guarded, zero-padded to K1p; A2: bf16 [M, lda2]
//   Bt: bf16 [N, Kp] transposed weights, Kp = K1p + K2 (A2 k-extent)
// 128x128 tile, BK=64, 4 waves, 4x4 accs of 16x16x32.
//
// LDS bank-conflict fix (R7): XOR k-chunk swizzle. LDS slot (row r, slot s)
// holds global k-chunk s ^ (r&7): staging lane i fetches chunk (i&7)^(i>>3);
// frag reads address slot chunk^(r&7). Row stride stays 64 (gl_lds-compatible)
// but a frag read's 16 rows now span 8 bank-groups -> 2-way (free) instead of
// the 16-way conflict of the linear layout (was 2.8e7 conflict cycles/disp).
//
// Epilogue: accs -> bf16 LDS tile Ct[128][128] (overlaps As+Bs; LDS=32KB)
// -> coalesced uint4 stores; bias/addm read there. In-place C==addm safe.
// SWZ: same-row-block tiles on one XCD (L2 A-reuse); needs gridY%8==0.
// ---------------------------------------------------------------------------
template<bool HAS_A1, bool HAS_A2, bool RELU, bool HAS_BIAS, bool HAS_ADD, bool SWZ>
__global__ __launch_bounds__(256)
void gemm_bt(const float* __restrict__ A1, int Kv1, int K1p,
             const unsigned short* __restrict__ A2, int lda2, int Kp,
             const unsigned short* __restrict__ Bt,
             const float* __restrict__ bias,
             const unsigned short* __restrict__ addm,
             unsigned short* __restrict__ C, int M, int N)
{
    __shared__ unsigned short lds[128 * 128];        // 32768 B exactly
    unsigned short* As = lds;                        // [128][64] swizzled
    unsigned short* Bs = lds + 128 * 64;             // [128][64] swizzled
    unsigned short* Ct = lds;                        // [128][128] (epilogue)

    const int tid  = threadIdx.x;
    const int lane = tid & 63;
    const int wid  = tid >> 6;
    int bx, by;
    if (SWZ) {
        int L = blockIdx.y * gridDim.x + blockIdx.x;
        int xcd = L & 7, s = L >> 3;
        bx = s % gridDim.x;
        by = xcd + 8 * (s / gridDim.x);
    } else { bx = blockIdx.x; by = blockIdx.y; }
    const int row0 = by * 128;
    const int col0 = bx * 128;
    const int wm   = wid & 1, wn = wid >> 1;
    const int quad = lane >> 4, l15 = lane & 15;
    const int srow = lane >> 3;                  // 0..7 row within 8-row slab
    const int ssw  = ((lane & 7) ^ srow) * 8;    // swizzled k-chunk to fetch

    f32x4 acc[4][4];
#pragma unroll
    for (int i = 0; i < 4; ++i)
#pragma unroll
        for (int j = 0; j < 4; ++j)
#pragma unroll
            for (int r = 0; r < 4; ++r) acc[i][j][r] = 0.f;

    for (int k0 = 0; k0 < Kp; k0 += 64) {
        __syncthreads();
        if (HAS_A1 && k0 < K1p) {
            bool kfull = (k0 + 63 < Kv1);
#pragma unroll
            for (int i = 0; i < 4; ++i) {
                int v = tid + i * 256;
                int m = v >> 3;
                int cs = ((v & 7) ^ (m & 7)) * 8;    // swizzled global chunk
                int r = row0 + m;
                const float* Arow = A1 + (size_t)r * Kv1;
                bool rok = (r < M);
                float f[8];
                if (kfull) {
#pragma unroll
                    for (int e = 0; e < 8; ++e) f[e] = rok ? Arow[k0 + cs + e] : 0.f;
                } else {
#pragma unroll
                    for (int e = 0; e < 8; ++e) {
                        int gk = k0 + cs + e;
                        f[e] = (rok && gk < Kv1) ? Arow[gk] : 0.f;
                    }
                }
                uint4 u;
                u.x = pk2bf(f[0], f[1]); u.y = pk2bf(f[2], f[3]);
                u.z = pk2bf(f[4], f[5]); u.w = pk2bf(f[6], f[7]);
                *(uint4*)&As[m * 64 + (v & 7) * 8] = u;
            }
        } else if (HAS_A2) {
            int kof = HAS_A1 ? (k0 - K1p) : k0;
#pragma unroll
            for (int i = 0; i < 4; ++i) {
                int mbase = wid * 32 + i * 8;                 // wave-uniform
                int r = row0 + mbase + srow;
                gl_lds16(A2 + (size_t)r * lda2 + kof + ssw, &As[mbase * 64]);
            }
        }
#pragma unroll
        for (int i = 0; i < 4; ++i) {
            int nbase = wid * 32 + i * 8;                     // wave-uniform
            int rn = col0 + nbase + srow;
            gl_lds16(Bt + (size_t)rn * Kp + k0 + ssw, &Bs[nbase * 64]);
        }
        __syncthreads();
#pragma unroll
        for (int ks = 0; ks < 2; ++ks) {
            int chunk = ks * 4 + quad;
            int slotA = (chunk ^ (l15 & 7)) * 8;   // same for A and B rows
            short8 a[4], b[4];
#pragma unroll
            for (int mt = 0; mt < 4; ++mt)
                a[mt] = *(const short8*)&As[(wm * 64 + mt * 16 + l15) * 64 + slotA];
#pragma unroll
            for (int nt = 0; nt < 4; ++nt)
                b[nt] = *(const short8*)&Bs[(wn * 64 + nt * 16 + l15) * 64 + slotA];
#pragma unroll
            for (int mt = 0; mt < 4; ++mt)
#pragma unroll
                for (int nt = 0; nt < 4; ++nt)
                    acc[mt][nt] = __builtin_amdgcn_mfma_f32_16x16x32_bf16(
                        a[mt], b[nt], acc[mt][nt], 0, 0, 0);
        }
    }

    // ---- epilogue: accs -> Ct[128][128] -> coalesced stores
    __syncthreads();
#pragma unroll
    for (int mt = 0; mt < 4; ++mt)
#pragma unroll
        for (int nt = 0; nt < 4; ++nt) {
            int cbase = wn * 64 + nt * 16 + l15;
            int rbase = wm * 64 + mt * 16 + quad * 4;
#pragma unroll
            for (int r = 0; r < 4; ++r)
                Ct[(rbase + r) * 128 + cbase] = f2bf(acc[mt][nt][r]);
        }
    __syncthreads();
#pragma unroll
    for (int i = 0; i < 8; ++i) {
        int c = tid + i * 256;                 // 0..2047
        int rr = c >> 4, cc = (c & 15) * 8;
        int m = row0 + rr, n = col0 + cc;
        short8 v = *(const short8*)&Ct[rr * 128 + cc];
        float f[8];
#pragma unroll
        for (int q = 0; q < 8; ++q) f[q] = bf2f((unsigned short)v[q]);
        if (HAS_BIAS) {
            float4 b0 = *(const float4*)(bias + n);
            float4 b1 = *(const float4*)(bias + n + 4);
            f[0] += b0.x; f[1] += b0.y; f[2] += b0.z; f[3] += b0.w;
            f[4] += b1.x; f[5] += b1.y; f[6] += b1.z; f[7] += b1.w;
        }
        if (m < M) {
            if (HAS_ADD) {
                uint4 ad = *(const uint4*)(addm + (size_t)m * N + n);
                unsigned int aw[4] = {ad.x, ad.y, ad.z, ad.w};
#pragma unroll
                for (int q = 0; q < 4; ++q) {
                    f[2 * q]     += __uint_as_float(aw[q] << 16);
                    f[2 * q + 1] += __uint_as_float(aw[q] & 0xFFFF0000u);
                }
            }
            if (RELU)
#pragma unroll
                for (int q = 0; q < 8; ++q) f[q] = fmaxf(f[q], 0.f);
            uint4 o;
            o.x = pk2bf(f[0], f[1]); o.y = pk2bf(f[2], f[3]);
            o.z = pk2bf(f[4], f[5]); o.w = pk2bf(f[6], f[7]);
            *(uint4*)(C + (size_t)m * N + n) = o;
        }
    }
}

// ---------------------------------------------------------------------------
// transpose + fp32->bf16: out[n*ldOut + koff + k] = in[k][n] (k in [0,Kz) of
// source; zero for k in [K, Kz))
// ---------------------------------------------------------------------------
__global__ __launch_bounds__(256)
void transpose_bf16(const float* __restrict__ in, int K, int N,
                    unsigned short* __restrict__ out, int ldOut, int Kz, int koff)
{
    __shared__ float t[32][33];
    const int n0 = blockIdx.x * 32, k0 = blockIdx.y * 32;
    const int tx = threadIdx.x & 31, ty = threadIdx.x >> 5;
#pragma unroll
    for (int i = 0; i < 32; i += 8) {
        int k = k0 + ty + i, n = n0 + tx;
        t[ty + i][tx] = (k < K && n < N) ? in[(size_t)k * N + n] : 0.f;
    }
    __syncthreads();
#pragma unroll
    for (int i = 0; i < 32; i += 8) {
        int n = n0 + ty + i, k = k0 + tx;
        if (n < N && k < Kz)
            out[(size_t)n * ldOut + koff + k] = f2bf(t[tx][ty + i]);
    }
}

// transpose of (A + B): out[n*ldOut + koff + k] = bf16(A[k][n] + B[k][n])
__global__ __launch_bounds__(256)
void transpose_add_bf16(const float* __restrict__ inA, const float* __restrict__ inB,
                        int K, int N, unsigned short* __restrict__ out,
                        int ldOut, int koff)
{
    __shared__ float t[32][33];
    const int n0 = blockIdx.x * 32, k0 = blockIdx.y * 32;
    const int tx = threadIdx.x & 31, ty = threadIdx.x >> 5;
#pragma unroll
    for (int i = 0; i < 32; i += 8) {
        int k = k0 + ty + i, n = n0 + tx;
        float v = 0.f;
        if (k < K && n < N) {
            v = inA[(size_t)k * N + n];
            if (inB) v += inB[(size_t)k * N + n];
        }
        t[ty + i][tx] = v;
    }
    __syncthreads();
#pragma unroll
    for (int i = 0; i < 32; i += 8) {
        int n = n0 + ty + i, k = k0 + tx;
        if (n < N && k < K)
            out[(size_t)n * ldOut + koff + k] = f2bf(t[tx][ty + i]);
    }
}

// ---------------------------------------------------------------------------
template<bool RELU>
__global__ __launch_bounds__(256)
void gather_kernel(const unsigned short* __restrict__ src,
                   const int* __restrict__ nei, unsigned short* __restrict__ dst)
{
    const int atom = blockIdx.x * 4 + (threadIdx.x >> 6);
    const int lane = threadIdx.x & 63;
    const int off  = lane * 8;
    const int* np_ = nei + (size_t)atom * MAX_NEI;
    float s[8];
#pragma unroll
    for (int e = 0; e < 8; ++e) s[e] = 0.f;
#pragma unroll
    for (int j = 0; j < MAX_NEI; ++j) {
        int idx = np_[j];
        uint4 u = *(const uint4*)(src + (size_t)idx * HIDDEN + off);
        unsigned int w[4] = {u.x, u.y, u.z, u.w};
#pragma unroll
        for (int q = 0; q < 4; ++q) {
            float lo = __uint_as_float(w[q] << 16);
            float hi = __uint_as_float(w[q] & 0xFFFF0000u);
            if (RELU) { lo = fmaxf(lo, 0.f); hi = fmaxf(hi, 0.f); }
            s[2 * q]     += lo;
            s[2 * q + 1] += hi;
        }
    }
    uint4 o;
    o.x = pk2bf(s[0], s[1]); o.y = pk2bf(s[2], s[3]);
    o.z = pk2bf(s[4], s[5]); o.w = pk2bf(s[6], s[7]);
    *(uint4*)(dst + (size_t)atom * HIDDEN + off) = o;
}

// ---------------------------------------------------------------------------
__global__ __launch_bounds__(256)
void segmean_kernel(const unsigned short* __restrict__ H,
                    const int* __restrict__ mol_ids, float* __restrict__ molv)
{
    const int m = blockIdx.x;
    const int d = threadIdx.x * 2;
    int lo = 0, hi = N_ATOMS;
    while (lo < hi) { int mid = (lo + hi) >> 1; if (mol_ids[mid] < m) lo = mid + 1; else hi = mid; }
    const int start = lo;
    hi = N_ATOMS;
    while (lo < hi) { int mid = (lo + hi) >> 1; if (mol_ids[mid] < m + 1) lo = mid + 1; else hi = mid; }
    const int end = lo;
    float s0 = 0.f, s1 = 0.f;
    for (int a = start; a < end; ++a) {
        unsigned int u = *(const unsigned int*)(H + (size_t)a * HIDDEN + d);
        s0 += __uint_as_float(u << 16);
        s1 += __uint_as_float(u & 0xFFFF0000u);
    }
    int cnt = end - start;
    float inv = 1.0f / (float)(cnt > 0 ? cnt : 1);
    float2 o; o.x = s0 * inv; o.y = s1 * inv;
    *(float2*)(molv + (size_t)m * HIDDEN + d) = o;
}

// ---------------------------------------------------------------------------
// feature[p,:] = [e1 | e2 | e1*e2]  (K=1536; matches [W0+W2; W0+W3; W1])
// ---------------------------------------------------------------------------
__global__ __launch_bounds__(128)
void feature_kernel(const float* __restrict__ molv, const int* __restrict__ edges,
                    unsigned short* __restrict__ feat)
{
    const int p  = blockIdx.x;
    const int d4 = threadIdx.x * 4;
    const int i  = edges[p];
    const int j  = edges[N_PAIRS + p];
    float4 a = *(const float4*)(molv + (size_t)i * HIDDEN + d4);
    float4 b = *(const float4*)(molv + (size_t)j * HIDDEN + d4);
    unsigned short* o = feat + (size_t)p * 1536;
    uint2 w;
    w.x = pk2bf(a.x, a.y); w.y = pk2bf(a.z, a.w);
    *(uint2*)(o + d4) = w;
    w.x = pk2bf(b.x, b.y); w.y = pk2bf(b.z, b.w);
    *(uint2*)(o + HIDDEN + d4) = w;
    w.x = pk2bf(a.x * b.x, a.y * b.y); w.y = pk2bf(a.z * b.z, a.w * b.w);
    *(uint2*)(o + 2 * HIDDEN + d4) = w;
}

// ---------------------------------------------------------------------------
__global__ __launch_bounds__(256)
void final_kernel(const unsigned short* __restrict__ H, const float* __restrict__ w,
                  const float* __restrict__ b, float* __restrict__ out)
{
    const int p   = blockIdx.x;
    const int tid = threadIdx.x;
    const unsigned short* row = H + (size_t)p * 1024;
    float s = 0.f;
    for (int i = tid; i < 1024; i += 256) s += bf2f(row[i]) * w[i];
#pragma unroll
    for (int off = 32; off > 0; off >>= 1) s += __shfl_down(s, off, 64);
    __shared__ float red[4];
    if ((tid & 63) == 0) red[tid >> 6] = s;
    __syncthreads();
    if (tid == 0) {
        float t = red[0] + red[1] + red[2] + red[3] + b[0];
        out[p] = 1.0f / (1.0f + expf(-t));
    }
}

// ---------------------------------------------------------------------------
// Workspace (peak 206.44 MB < proven-safe 213.2 MB):
//   I    bf16 [100000,512] @ 0
//   Y    bf16 [100000,512] @ 102,400,000
//   Wt_i bf16 [512,192]    @ 204,800,000
//   Wch  bf16 [512,512]    @ 204,996,608   (W_h^T; step 3 K=512)
//   Wco  bf16 [512,704]    @ 205,520,896   ([W_o1|W_o2]^T) ends ~206.24 MB
//   after Y dies: Mv fp32 [4096,512] @ Y; Wt_f0 bf16 [2048,1536] @ Y+16MB;
//                 Wt_f1 bf16 [1024,2048] after it
//   after I dies: F bf16[8192,1536] / H1[8192,2048] / H2[8192,1024] in I region
// OOB note: padded 784-row grids read A2/addm rows < 100352 -> Y+102.76 MB =
// ws offset 205.2 MB, inside allocated ws (garbage, discarded; addm guarded).
// ---------------------------------------------------------------------------
extern "C" void kernel_launch(void* const* d_in, const int* in_sizes, int n_in,
                              void* d_out, int out_size, void* d_ws, size_t ws_size,
                              hipStream_t stream)
{
    const float* f_atoms = (const float*)d_in[0];
    const int*   a_nei   = (const int*)d_in[1];
    const int*   mol_ids = (const int*)d_in[2];
    const int*   edges   = (const int*)d_in[3];
    const float* W_i     = (const float*)d_in[4];
    const float* W_h     = (const float*)d_in[5];
    const float* W_o     = (const float*)d_in[6];
    const float* b_o     = (const float*)d_in[7];
    const float* W_ffn_i = (const float*)d_in[8];
    const float* b_ffn_i = (const float*)d_in[9];
    const float* W_ffn_1 = (const float*)d_in[10];
    const float* b_ffn_1 = (const float*)d_in[11];
    const float* W_ffn_2 = (const float*)d_in[12];
    const float* b_ffn_2 = (const float*)d_in[13];
    float* out = (float*)d_out;

    char* ws = (char*)d_ws;
    unsigned short* I     = (unsigned short*)ws;
    unsigned short* Y     = (unsigned short*)(ws + 102400000);
    unsigned short* Wt_i  = (unsigned short*)(ws + 204800000);
    unsigned short* Wch   = Wt_i + 512 * 192;
    unsigned short* Wco   = Wch  + 512 * 512;
    float*          Mv    = (float*)(ws + 102400000);
    unsigned short* Wt_f0 = (unsigned short*)(ws + 102400000 + 16777216);
    unsigned short* Wt_f1 = Wt_f0 + (size_t)2048 * 1536;
    unsigned short* F     = (unsigned short*)ws;
    unsigned short* H1    = F  + (size_t)N_PAIRS * 1536;
    unsigned short* H2    = H1 + (size_t)N_PAIRS * 2048;

    const float* W0 = W_ffn_i;
    const float* W1 = W_ffn_i + (size_t)512 * 2048;
    const float* W2 = W_ffn_i + (size_t)1024 * 2048;
    const float* W3 = W_ffn_i + (size_t)1536 * 2048;

    // --- weight prep (atom-phase) ---
    transpose_bf16<<<dim3(16, 6),  256, 0, stream>>>(W_i, 133, 512, Wt_i, 192, 192, 0);
    transpose_bf16<<<dim3(16, 16), 256, 0, stream>>>(W_h, 512, 512, Wch, 512, 512, 0);
    transpose_bf16<<<dim3(16, 6),  256, 0, stream>>>(W_o, 133, 512, Wco, 704, 192, 0);
    transpose_bf16<<<dim3(16, 16), 256, 0, stream>>>(W_o + (size_t)133 * 512,
                                                     512, 512, Wco, 704, 512, 192);

    // 1) I = f_atoms @ W_i   (pre-relu inp; also addm for step 3)
    gemm_bt<true, false, false, false, false, true><<<dim3(4, 784), 256, 0, stream>>>(
        f_atoms, 133, 192, nullptr, 0, 192, Wt_i, nullptr, nullptr, I, N_ATOMS, HIDDEN);
    // 2) Y = gather-sum(relu(I))
    gather_kernel<true><<<N_ATOMS / 4, 256, 0, stream>>>(I, a_nei, Y);
    // 3) I = relu(I + Y @ W_h)     (in-place addm, K=512)
    gemm_bt<false, true, true, false, true, true><<<dim3(4, 784), 256, 0, stream>>>(
        nullptr, 0, 0, Y, 512, 512, Wch, nullptr, I, I, N_ATOMS, HIDDEN);
    // 4) Y = gather-sum(I)
    gather_kernel<false><<<N_ATOMS / 4, 256, 0, stream>>>(I, a_nei, Y);
    // 5) I = relu([f_atoms | Y] @ [W_o1 ; W_o2] + b_o)   (concat-K, K=704)
    gemm_bt<true, true, true, true, false, true><<<dim3(4, 784), 256, 0, stream>>>(
        f_atoms, 133, 192, Y, 512, 704, Wco, b_o, nullptr, I, N_ATOMS, HIDDEN);
    // 6) Mv = segment-mean(I)            (Y region; Y dead)
    segmean_kernel<<<N_MOLS, 256, 0, stream>>>(I, mol_ids, Mv);
    // FFN weight prep: Wt_f0 = [(W0+W2); (W0+W3); W1]^T  [2048 x 1536]
    transpose_add_bf16<<<dim3(64, 16), 256, 0, stream>>>(W0, W2, 512, 2048, Wt_f0, 1536, 0);
    transpose_add_bf16<<<dim3(64, 16), 256, 0, stream>>>(W0, W3, 512, 2048, Wt_f0, 1536, 512);
    transpose_add_bf16<<<dim3(64, 16), 256, 0, stream>>>(W1, nullptr, 512, 2048, Wt_f0, 1536, 1024);
    transpose_bf16<<<dim3(32, 64), 256, 0, stream>>>(W_ffn_1, 2048, 1024, Wt_f1, 2048, 2048, 0);
    // 7) F = [e1 | e2 | e1*e2]           (I region; I dead)
    feature_kernel<<<N_PAIRS, 128, 0, stream>>>(Mv, edges, F);
    // 8) H1 = relu(F @ Wt_f0^T + b_ffn_i)   (K=1536)
    gemm_bt<false, true, true, true, false, true><<<dim3(16, 64), 256, 0, stream>>>(
        nullptr, 0, 0, F, 1536, 1536, Wt_f0, b_ffn_i, nullptr, H1, N_PAIRS, 2048);
    // 9) H2 = relu(H1 @ W_ffn_1 + b_ffn_1)  (K=2048)
    gemm_bt<false, true, true, true, false, true><<<dim3(8, 64), 256, 0, stream>>>(
        nullptr, 0, 0, H1, 2048, 2048, Wt_f1, b_ffn_1, nullptr, H2, N_PAIRS, 1024);
    // 10) out = sigmoid(H2 @ W_ffn_2 + b_ffn_2)
    final_kernel<<<N_PAIRS, 256, 0, stream>>>(H2, W_ffn_2, b_ffn_2, out);
    (void)in_sizes; (void)n_in; (void)out_size; (void)ws_size;
}

// Round 8
// 662.956 us; speedup vs baseline: 9.1523x; 1.2163x over previous
//
#include <hip/hip_runtime.h>
#include <math.h>

#define N_ATOMS   100000
#define ATOM_FDIM 133
#define HIDDEN    512
#define MAX_NEI   6
#define N_MOLS    4096
#define N_PAIRS   8192

typedef __attribute__((ext_vector_type(8))) short short8;
typedef __attribute__((ext_vector_type(4))) float f32x4;
typedef __attribute__((ext_vector_type(2))) float f32x2;
typedef __attribute__((ext_vector_type(8))) int int8v;

static __device__ __forceinline__ float bf2f(unsigned short h) {
    return __uint_as_float(((unsigned int)h) << 16);
}
static __device__ __forceinline__ unsigned short f2bf(float f) {
    unsigned int u = __float_as_uint(f);
    u += 0x7FFFu + ((u >> 16) & 1u);
    return (unsigned short)(u >> 16);
}
static __device__ __forceinline__ unsigned int pk2bf(float a, float b) {
    unsigned int ua = __float_as_uint(a); ua += 0x7FFFu + ((ua >> 16) & 1u);
    unsigned int ub = __float_as_uint(b); ub += 0x7FFFu + ((ub >> 16) & 1u);
    return (ua >> 16) | (ub & 0xFFFF0000u);
}
// 4x fp32 -> 4x fp8 e4m3 (OCP) packed in a uint
static __device__ __forceinline__ unsigned int pk4f8(float a, float b, float c, float d) {
    unsigned int r = 0;
    r = __builtin_amdgcn_cvt_pk_fp8_f32(a, b, r, false);
    r = __builtin_amdgcn_cvt_pk_fp8_f32(c, d, r, true);
    return r;
}
static __device__ __forceinline__ void gl_lds16(const void* g, void* l) {
    __builtin_amdgcn_global_load_lds(
        (__attribute__((address_space(1))) void*)g,
        (__attribute__((address_space(3))) void*)l, 16, 0, 0);
}

// ---------------------------------------------------------------------------
// MX-fp8 (unit scale) MFMA GEMM:
//   C(fp8[M,N]) = act( [A1_f32 | A2_fp8] @ Bt^T [+bias] [+addm_fp8] )
//   A1: fp32 [M,Kv1] guarded, zero-pad to K1p (mult of 128)
//   A2: fp8 [M, lda2]; Bt: fp8 [N, Kp]; Kp mult of 128
// 128x128 tile, BK=128, 4 waves, 4x4 accs of 16x16x128 f8f6f4 (scale=1.0).
// LDS: As/Bs fp8 [128][128] (16 KB each, 32 KB total), XOR 16B-chunk swizzle:
// slot s of row r holds global chunk s^(r&7) -> frag reads 2-way (free).
// Epilogue: accs -> bf16 Ct[128][128] (reuses As+Bs) -> fp8 coalesced stores.
// In-place C==addm safe. SWZ: row-block -> XCD (needs gridY%8==0).
// ---------------------------------------------------------------------------
template<bool HAS_A1, bool RELU, bool HAS_BIAS, bool HAS_ADD, bool SWZ>
__global__ __launch_bounds__(256)
void gemm_f8(const float* __restrict__ A1, int Kv1, int K1p,
             const unsigned char* __restrict__ A2, int lda2, int Kp,
             const unsigned char* __restrict__ Bt,
             const float* __restrict__ bias,
             const unsigned char* __restrict__ addm,
             unsigned char* __restrict__ C, int M, int N)
{
    __shared__ unsigned char lds[128 * 256];         // 32768 B
    unsigned char* As = lds;                         // fp8 [128][128]
    unsigned char* Bs = lds + 128 * 128;             // fp8 [128][128]
    unsigned short* Ct = (unsigned short*)lds;       // bf16 [128][128] epilogue

    const int tid  = threadIdx.x;
    const int lane = tid & 63;
    const int wid  = tid >> 6;
    int bx, by;
    if (SWZ) {
        int L = blockIdx.y * gridDim.x + blockIdx.x;
        int xcd = L & 7, s = L >> 3;
        bx = s % gridDim.x;
        by = xcd + 8 * (s / gridDim.x);
    } else { bx = blockIdx.x; by = blockIdx.y; }
    const int row0 = by * 128;
    const int col0 = bx * 128;
    const int wm   = wid & 1, wn = wid >> 1;
    const int quad = lane >> 4, l15 = lane & 15;
    const int srow = lane >> 3, schunk = lane & 7;
    const int ssw  = (schunk ^ srow) * 16;           // swizzled global 16B chunk

    f32x4 acc[4][4];
#pragma unroll
    for (int i = 0; i < 4; ++i)
#pragma unroll
        for (int j = 0; j < 4; ++j)
#pragma unroll
            for (int r = 0; r < 4; ++r) acc[i][j][r] = 0.f;

    for (int k0 = 0; k0 < Kp; k0 += 128) {
        __syncthreads();
        if (HAS_A1 && k0 < K1p) {
            // fp32 -> fp8 convert staging: 128 rows x 8 slots, 4 cells/thread
#pragma unroll
            for (int i = 0; i < 4; ++i) {
                int v = tid + i * 256;
                int m = v >> 3, sl = v & 7;
                int gk = k0 + ((sl ^ (m & 7)) * 16);
                int r = row0 + m;
                bool rok = (r < M);
                const float* Arow = A1 + (size_t)r * Kv1;
                float f[16];
#pragma unroll
                for (int e = 0; e < 16; ++e) {
                    int kk = gk + e;
                    f[e] = (rok && kk < Kv1) ? Arow[kk] : 0.f;
                }
                uint4 u;
                u.x = pk4f8(f[0], f[1], f[2], f[3]);
                u.y = pk4f8(f[4], f[5], f[6], f[7]);
                u.z = pk4f8(f[8], f[9], f[10], f[11]);
                u.w = pk4f8(f[12], f[13], f[14], f[15]);
                *(uint4*)&As[m * 128 + sl * 16] = u;
            }
        } else {
            int kof = HAS_A1 ? (k0 - K1p) : k0;
#pragma unroll
            for (int i = 0; i < 4; ++i) {
                int mbase = wid * 32 + i * 8;                 // wave-uniform
                int r = row0 + mbase + srow;
                gl_lds16(A2 + (size_t)r * lda2 + kof + ssw, &As[mbase * 128]);
            }
        }
#pragma unroll
        for (int i = 0; i < 4; ++i) {
            int nbase = wid * 32 + i * 8;                     // wave-uniform
            int rn = col0 + nbase + srow;
            gl_lds16(Bt + (size_t)rn * Kp + k0 + ssw, &Bs[nbase * 128]);
        }
        __syncthreads();
        // fragment loads: lane holds k = quad*32 .. +31 (chunks 2q, 2q+1)
        const int s0 = ((2 * quad) ^ (l15 & 7)) * 16;
        const int s1 = ((2 * quad + 1) ^ (l15 & 7)) * 16;
        int8v a[4], b[4];
#pragma unroll
        for (int mt = 0; mt < 4; ++mt) {
            int r = wm * 64 + mt * 16 + l15;
            uint4 lo = *(const uint4*)&As[r * 128 + s0];
            uint4 hi = *(const uint4*)&As[r * 128 + s1];
            a[mt][0] = lo.x; a[mt][1] = lo.y; a[mt][2] = lo.z; a[mt][3] = lo.w;
            a[mt][4] = hi.x; a[mt][5] = hi.y; a[mt][6] = hi.z; a[mt][7] = hi.w;
        }
#pragma unroll
        for (int nt = 0; nt < 4; ++nt) {
            int r = wn * 64 + nt * 16 + l15;
            uint4 lo = *(const uint4*)&Bs[r * 128 + s0];
            uint4 hi = *(const uint4*)&Bs[r * 128 + s1];
            b[nt][0] = lo.x; b[nt][1] = lo.y; b[nt][2] = lo.z; b[nt][3] = lo.w;
            b[nt][4] = hi.x; b[nt][5] = hi.y; b[nt][6] = hi.z; b[nt][7] = hi.w;
        }
#pragma unroll
        for (int mt = 0; mt < 4; ++mt)
#pragma unroll
            for (int nt = 0; nt < 4; ++nt)
                acc[mt][nt] = __builtin_amdgcn_mfma_scale_f32_16x16x128_f8f6f4(
                    a[mt], b[nt], acc[mt][nt], 0, 0, 0, 127, 0, 127);
    }

    // ---- epilogue: accs -> bf16 Ct -> fp8 coalesced stores
    __syncthreads();
#pragma unroll
    for (int mt = 0; mt < 4; ++mt)
#pragma unroll
        for (int nt = 0; nt < 4; ++nt) {
            int cbase = wn * 64 + nt * 16 + l15;
            int rbase = wm * 64 + mt * 16 + quad * 4;
#pragma unroll
            for (int r = 0; r < 4; ++r)
                Ct[(rbase + r) * 128 + cbase] = f2bf(acc[mt][nt][r]);
        }
    __syncthreads();
#pragma unroll
    for (int i = 0; i < 8; ++i) {
        int c = tid + i * 256;                 // 0..2047
        int rr = c >> 4, cc = (c & 15) * 8;
        int m = row0 + rr, n = col0 + cc;
        short8 v = *(const short8*)&Ct[rr * 128 + cc];
        float f[8];
#pragma unroll
        for (int q = 0; q < 8; ++q) f[q] = bf2f((unsigned short)v[q]);
        if (HAS_BIAS) {
            float4 b0 = *(const float4*)(bias + n);
            float4 b1 = *(const float4*)(bias + n + 4);
            f[0] += b0.x; f[1] += b0.y; f[2] += b0.z; f[3] += b0.w;
            f[4] += b1.x; f[5] += b1.y; f[6] += b1.z; f[7] += b1.w;
        }
        if (m < M) {
            if (HAS_ADD) {
                uint2 ad = *(const uint2*)(addm + (size_t)m * N + n);
                f32x2 p;
                p = __builtin_amdgcn_cvt_pk_f32_fp8(ad.x, false); f[0] += p.x; f[1] += p.y;
                p = __builtin_amdgcn_cvt_pk_f32_fp8(ad.x, true);  f[2] += p.x; f[3] += p.y;
                p = __builtin_amdgcn_cvt_pk_f32_fp8(ad.y, false); f[4] += p.x; f[5] += p.y;
                p = __builtin_amdgcn_cvt_pk_f32_fp8(ad.y, true);  f[6] += p.x; f[7] += p.y;
            }
            if (RELU)
#pragma unroll
                for (int q = 0; q < 8; ++q) f[q] = fmaxf(f[q], 0.f);
            uint2 o;
            o.x = pk4f8(f[0], f[1], f[2], f[3]);
            o.y = pk4f8(f[4], f[5], f[6], f[7]);
            *(uint2*)(C + (size_t)m * N + n) = o;
        }
    }
}

// ---------------------------------------------------------------------------
// bf16 MFMA GEMM (FFN path) — unchanged from R7.
// ---------------------------------------------------------------------------
template<bool RELU, bool HAS_BIAS, bool SWZ>
__global__ __launch_bounds__(256)
void gemm_bt(const unsigned short* __restrict__ A2, int lda2, int Kp,
             const unsigned short* __restrict__ Bt,
             const float* __restrict__ bias,
             unsigned short* __restrict__ C, int M, int N)
{
    __shared__ unsigned short lds[128 * 128];
    unsigned short* As = lds;
    unsigned short* Bs = lds + 128 * 64;
    unsigned short* Ct = lds;

    const int tid  = threadIdx.x;
    const int lane = tid & 63;
    const int wid  = tid >> 6;
    int bx, by;
    if (SWZ) {
        int L = blockIdx.y * gridDim.x + blockIdx.x;
        int xcd = L & 7, s = L >> 3;
        bx = s % gridDim.x;
        by = xcd + 8 * (s / gridDim.x);
    } else { bx = blockIdx.x; by = blockIdx.y; }
    const int row0 = by * 128;
    const int col0 = bx * 128;
    const int wm   = wid & 1, wn = wid >> 1;
    const int quad = lane >> 4, l15 = lane & 15;
    const int srow = lane >> 3;
    const int ssw  = ((lane & 7) ^ srow) * 8;

    f32x4 acc[4][4];
#pragma unroll
    for (int i = 0; i < 4; ++i)
#pragma unroll
        for (int j = 0; j < 4; ++j)
#pragma unroll
            for (int r = 0; r < 4; ++r) acc[i][j][r] = 0.f;

    for (int k0 = 0; k0 < Kp; k0 += 64) {
        __syncthreads();
#pragma unroll
        for (int i = 0; i < 4; ++i) {
            int mbase = wid * 32 + i * 8;
            int r = row0 + mbase + srow;
            gl_lds16(A2 + (size_t)r * lda2 + k0 + ssw, &As[mbase * 64]);
        }
#pragma unroll
        for (int i = 0; i < 4; ++i) {
            int nbase = wid * 32 + i * 8;
            int rn = col0 + nbase + srow;
            gl_lds16(Bt + (size_t)rn * Kp + k0 + ssw, &Bs[nbase * 64]);
        }
        __syncthreads();
#pragma unroll
        for (int ks = 0; ks < 2; ++ks) {
            int chunk = ks * 4 + quad;
            int slotA = (chunk ^ (l15 & 7)) * 8;
            short8 a[4], b[4];
#pragma unroll
            for (int mt = 0; mt < 4; ++mt)
                a[mt] = *(const short8*)&As[(wm * 64 + mt * 16 + l15) * 64 + slotA];
#pragma unroll
            for (int nt = 0; nt < 4; ++nt)
                b[nt] = *(const short8*)&Bs[(wn * 64 + nt * 16 + l15) * 64 + slotA];
#pragma unroll
            for (int mt = 0; mt < 4; ++mt)
#pragma unroll
                for (int nt = 0; nt < 4; ++nt)
                    acc[mt][nt] = __builtin_amdgcn_mfma_f32_16x16x32_bf16(
                        a[mt], b[nt], acc[mt][nt], 0, 0, 0);
        }
    }

    __syncthreads();
#pragma unroll
    for (int mt = 0; mt < 4; ++mt)
#pragma unroll
        for (int nt = 0; nt < 4; ++nt) {
            int cbase = wn * 64 + nt * 16 + l15;
            int rbase = wm * 64 + mt * 16 + quad * 4;
#pragma unroll
            for (int r = 0; r < 4; ++r)
                Ct[(rbase + r) * 128 + cbase] = f2bf(acc[mt][nt][r]);
        }
    __syncthreads();
#pragma unroll
    for (int i = 0; i < 8; ++i) {
        int c = tid + i * 256;
        int rr = c >> 4, cc = (c & 15) * 8;
        int m = row0 + rr, n = col0 + cc;
        short8 v = *(const short8*)&Ct[rr * 128 + cc];
        float f[8];
#pragma unroll
        for (int q = 0; q < 8; ++q) f[q] = bf2f((unsigned short)v[q]);
        if (HAS_BIAS) {
            float4 b0 = *(const float4*)(bias + n);
            float4 b1 = *(const float4*)(bias + n + 4);
            f[0] += b0.x; f[1] += b0.y; f[2] += b0.z; f[3] += b0.w;
            f[4] += b1.x; f[5] += b1.y; f[6] += b1.z; f[7] += b1.w;
        }
        if (RELU)
#pragma unroll
            for (int q = 0; q < 8; ++q) f[q] = fmaxf(f[q], 0.f);
        if (m < M) {
            uint4 o;
            o.x = pk2bf(f[0], f[1]); o.y = pk2bf(f[2], f[3]);
            o.z = pk2bf(f[4], f[5]); o.w = pk2bf(f[6], f[7]);
            *(uint4*)(C + (size_t)m * N + n) = o;
        }
    }
}

// ---------------------------------------------------------------------------
// transposes: fp32 -> bf16 / fp8, zero-pad k in [K, Kz), offset koff
// ---------------------------------------------------------------------------
__global__ __launch_bounds__(256)
void transpose_bf16(const float* __restrict__ in, int K, int N,
                    unsigned short* __restrict__ out, int ldOut, int Kz, int koff)
{
    __shared__ float t[32][33];
    const int n0 = blockIdx.x * 32, k0 = blockIdx.y * 32;
    const int tx = threadIdx.x & 31, ty = threadIdx.x >> 5;
#pragma unroll
    for (int i = 0; i < 32; i += 8) {
        int k = k0 + ty + i, n = n0 + tx;
        t[ty + i][tx] = (k < K && n < N) ? in[(size_t)k * N + n] : 0.f;
    }
    __syncthreads();
#pragma unroll
    for (int i = 0; i < 32; i += 8) {
        int n = n0 + ty + i, k = k0 + tx;
        if (n < N && k < Kz)
            out[(size_t)n * ldOut + koff + k] = f2bf(t[tx][ty + i]);
    }
}

__global__ __launch_bounds__(256)
void transpose_f8(const float* __restrict__ in, int K, int N,
                  unsigned char* __restrict__ out, int ldOut, int Kz, int koff)
{
    __shared__ float t[32][33];
    const int n0 = blockIdx.x * 32, k0 = blockIdx.y * 32;
    const int tx = threadIdx.x & 31, ty = threadIdx.x >> 5;
#pragma unroll
    for (int i = 0; i < 32; i += 8) {
        int k = k0 + ty + i, n = n0 + tx;
        t[ty + i][tx] = (k < K && n < N) ? in[(size_t)k * N + n] : 0.f;
    }
    __syncthreads();
#pragma unroll
    for (int i = 0; i < 32; i += 8) {
        int n = n0 + ty + i, k = k0 + tx;
        if (n < N && k < Kz) {
            float v = t[tx][ty + i];
            out[(size_t)n * ldOut + koff + k] =
                (unsigned char)(__builtin_amdgcn_cvt_pk_fp8_f32(v, v, 0, false) & 0xFF);
        }
    }
}

// transpose of (A + B) -> bf16 (FFN fold)
__global__ __launch_bounds__(256)
void transpose_add_bf16(const float* __restrict__ inA, const float* __restrict__ inB,
                        int K, int N, unsigned short* __restrict__ out,
                        int ldOut, int koff)
{
    __shared__ float t[32][33];
    const int n0 = blockIdx.x * 32, k0 = blockIdx.y * 32;
    const int tx = threadIdx.x & 31, ty = threadIdx.x >> 5;
#pragma unroll
    for (int i = 0; i < 32; i += 8) {
        int k = k0 + ty + i, n = n0 + tx;
        float v = 0.f;
        if (k < K && n < N) {
            v = inA[(size_t)k * N + n];
            if (inB) v += inB[(size_t)k * N + n];
        }
        t[ty + i][tx] = v;
    }
    __syncthreads();
#pragma unroll
    for (int i = 0; i < 32; i += 8) {
        int n = n0 + ty + i, k = k0 + tx;
        if (n < N && k < K)
            out[(size_t)n * ldOut + koff + k] = f2bf(t[tx][ty + i]);
    }
}

// ---------------------------------------------------------------------------
// gather-sum over fp8: dst[a,:] = sum_j (RELU? relu:id)(src[nei[a,j],:])
// 8 atoms/block; 32 lanes x 16 fp8 per atom row (uint4)
// ---------------------------------------------------------------------------
template<bool RELU>
__global__ __launch_bounds__(256)
void gather_f8(const unsigned char* __restrict__ src,
               const int* __restrict__ nei, unsigned char* __restrict__ dst)
{
    const int atom = blockIdx.x * 8 + (threadIdx.x >> 5);
    const int l32  = threadIdx.x & 31;
    const int off  = l32 * 16;
    const int* np_ = nei + (size_t)atom * MAX_NEI;
    float s[16];
#pragma unroll
    for (int e = 0; e < 16; ++e) s[e] = 0.f;
#pragma unroll
    for (int j = 0; j < MAX_NEI; ++j) {
        uint4 u = *(const uint4*)(src + (size_t)np_[j] * HIDDEN + off);
        unsigned int w[4] = {u.x, u.y, u.z, u.w};
#pragma unroll
        for (int q = 0; q < 4; ++q) {
            f32x2 lo = __builtin_amdgcn_cvt_pk_f32_fp8(w[q], false);
            f32x2 hi = __builtin_amdgcn_cvt_pk_f32_fp8(w[q], true);
            float v0 = lo.x, v1 = lo.y, v2 = hi.x, v3 = hi.y;
            if (RELU) {
                v0 = fmaxf(v0, 0.f); v1 = fmaxf(v1, 0.f);
                v2 = fmaxf(v2, 0.f); v3 = fmaxf(v3, 0.f);
            }
            s[4 * q] += v0; s[4 * q + 1] += v1; s[4 * q + 2] += v2; s[4 * q + 3] += v3;
        }
    }
    uint4 o;
    o.x = pk4f8(s[0], s[1], s[2], s[3]);
    o.y = pk4f8(s[4], s[5], s[6], s[7]);
    o.z = pk4f8(s[8], s[9], s[10], s[11]);
    o.w = pk4f8(s[12], s[13], s[14], s[15]);
    *(uint4*)(dst + (size_t)atom * HIDDEN + off) = o;
}

// ---------------------------------------------------------------------------
// segment-mean over sorted mol_ids (fp8 in, fp32 out). Empty -> 0.
// ---------------------------------------------------------------------------
__global__ __launch_bounds__(256)
void segmean_f8(const unsigned char* __restrict__ H,
                const int* __restrict__ mol_ids, float* __restrict__ molv)
{
    const int m = blockIdx.x;
    const int d = threadIdx.x * 2;
    int lo = 0, hi = N_ATOMS;
    while (lo < hi) { int mid = (lo + hi) >> 1; if (mol_ids[mid] < m) lo = mid + 1; else hi = mid; }
    const int start = lo;
    hi = N_ATOMS;
    while (lo < hi) { int mid = (lo + hi) >> 1; if (mol_ids[mid] < m + 1) lo = mid + 1; else hi = mid; }
    const int end = lo;
    float s0 = 0.f, s1 = 0.f;
    for (int a = start; a < end; ++a) {
        unsigned int raw = *(const unsigned short*)(H + (size_t)a * HIDDEN + d);
        f32x2 f = __builtin_amdgcn_cvt_pk_f32_fp8(raw, false);
        s0 += f.x; s1 += f.y;
    }
    int cnt = end - start;
    float inv = 1.0f / (float)(cnt > 0 ? cnt : 1);
    float2 o; o.x = s0 * inv; o.y = s1 * inv;
    *(float2*)(molv + (size_t)m * HIDDEN + d) = o;
}

// ---------------------------------------------------------------------------
// feature[p,:] = [e1 | e2 | e1*e2]  (fp32 molv -> bf16, K=1536 FFN fold)
// ---------------------------------------------------------------------------
__global__ __launch_bounds__(128)
void feature_kernel(const float* __restrict__ molv, const int* __restrict__ edges,
                    unsigned short* __restrict__ feat)
{
    const int p  = blockIdx.x;
    const int d4 = threadIdx.x * 4;
    const int i  = edges[p];
    const int j  = edges[N_PAIRS + p];
    float4 a = *(const float4*)(molv + (size_t)i * HIDDEN + d4);
    float4 b = *(const float4*)(molv + (size_t)j * HIDDEN + d4);
    unsigned short* o = feat + (size_t)p * 1536;
    uint2 w;
    w.x = pk2bf(a.x, a.y); w.y = pk2bf(a.z, a.w);
    *(uint2*)(o + d4) = w;
    w.x = pk2bf(b.x, b.y); w.y = pk2bf(b.z, b.w);
    *(uint2*)(o + HIDDEN + d4) = w;
    w.x = pk2bf(a.x * b.x, a.y * b.y); w.y = pk2bf(a.z * b.z, a.w * b.w);
    *(uint2*)(o + 2 * HIDDEN + d4) = w;
}

// ---------------------------------------------------------------------------
__global__ __launch_bounds__(256)
void final_kernel(const unsigned short* __restrict__ H, const float* __restrict__ w,
                  const float* __restrict__ b, float* __restrict__ out)
{
    const int p   = blockIdx.x;
    const int tid = threadIdx.x;
    const unsigned short* row = H + (size_t)p * 1024;
    float s = 0.f;
    for (int i = tid; i < 1024; i += 256) s += bf2f(row[i]) * w[i];
#pragma unroll
    for (int off = 32; off > 0; off >>= 1) s += __shfl_down(s, off, 64);
    __shared__ float red[4];
    if ((tid & 63) == 0) red[tid >> 6] = s;
    __syncthreads();
    if (tid == 0) {
        float t = red[0] + red[1] + red[2] + red[3] + b[0];
        out[p] = 1.0f / (1.0f + expf(-t));
    }
}

// ---------------------------------------------------------------------------
// Workspace (peak 197.6 MB < proven-safe 213.2 MB; no region aliasing):
//   I     fp8 [100000,512] @ 0            (51.2 MB)
//   Y     fp8 [100000,512] @ 51,200,000   (51.2 MB)
//   Wt_i  fp8 [512,256]    @ 102,400,000
//   Wch   fp8 [512,512]    @ 102,531,072
//   Wco   fp8 [512,768]    @ 102,793,216  ([Wo1 pad256 | Wo2])
//   Mv    f32 [4096,512]   @ 103,186,432
//   Wt_f0 bf16[2048,1536]  @ 111,575,040
//   Wt_f1 bf16[1024,2048]  @ 117,866,496
//   F     bf16[8192,1536]  @ 122,060,800
//   H1    bf16[8192,2048]  @ 147,226,624
//   H2    bf16[8192,1024]  @ 180,781,056  -> end 197,558,272
// OOB: padded 784-row grids read A2/addm rows < 100352 -> < offset 102.6 MB,
// inside ws (garbage, feeds discarded rows; addm read guarded by m<M).
// ---------------------------------------------------------------------------
extern "C" void kernel_launch(void* const* d_in, const int* in_sizes, int n_in,
                              void* d_out, int out_size, void* d_ws, size_t ws_size,
                              hipStream_t stream)
{
    const float* f_atoms = (const float*)d_in[0];
    const int*   a_nei   = (const int*)d_in[1];
    const int*   mol_ids = (const int*)d_in[2];
    const int*   edges   = (const int*)d_in[3];
    const float* W_i     = (const float*)d_in[4];
    const float* W_h     = (const float*)d_in[5];
    const float* W_o     = (const float*)d_in[6];
    const float* b_o     = (const float*)d_in[7];
    const float* W_ffn_i = (const float*)d_in[8];
    const float* b_ffn_i = (const float*)d_in[9];
    const float* W_ffn_1 = (const float*)d_in[10];
    const float* b_ffn_1 = (const float*)d_in[11];
    const float* W_ffn_2 = (const float*)d_in[12];
    const float* b_ffn_2 = (const float*)d_in[13];
    float* out = (float*)d_out;

    char* ws = (char*)d_ws;
    unsigned char*  I     = (unsigned char*)ws;
    unsigned char*  Y     = (unsigned char*)(ws + 51200000);
    unsigned char*  Wt_i  = (unsigned char*)(ws + 102400000);
    unsigned char*  Wch   = (unsigned char*)(ws + 102531072);
    unsigned char*  Wco   = (unsigned char*)(ws + 102793216);
    float*          Mv    = (float*)(ws + 103186432);
    unsigned short* Wt_f0 = (unsigned short*)(ws + 111575040);
    unsigned short* Wt_f1 = (unsigned short*)(ws + 117866496);
    unsigned short* F     = (unsigned short*)(ws + 122060800);
    unsigned short* H1    = (unsigned short*)(ws + 147226624);
    unsigned short* H2    = (unsigned short*)(ws + 180781056);

    const float* W0 = W_ffn_i;
    const float* W1 = W_ffn_i + (size_t)512 * 2048;
    const float* W2 = W_ffn_i + (size_t)1024 * 2048;
    const float* W3 = W_ffn_i + (size_t)1536 * 2048;

    // --- all weight prep front-loaded ---
    transpose_f8<<<dim3(16, 8),  256, 0, stream>>>(W_i, 133, 512, Wt_i, 256, 256, 0);
    transpose_f8<<<dim3(16, 16), 256, 0, stream>>>(W_h, 512, 512, Wch, 512, 512, 0);
    transpose_f8<<<dim3(16, 8),  256, 0, stream>>>(W_o, 133, 512, Wco, 768, 256, 0);
    transpose_f8<<<dim3(16, 16), 256, 0, stream>>>(W_o + (size_t)133 * 512,
                                                   512, 512, Wco, 768, 512, 256);
    transpose_add_bf16<<<dim3(64, 16), 256, 0, stream>>>(W0, W2, 512, 2048, Wt_f0, 1536, 0);
    transpose_add_bf16<<<dim3(64, 16), 256, 0, stream>>>(W0, W3, 512, 2048, Wt_f0, 1536, 512);
    transpose_add_bf16<<<dim3(64, 16), 256, 0, stream>>>(W1, nullptr, 512, 2048, Wt_f0, 1536, 1024);
    transpose_bf16<<<dim3(32, 64), 256, 0, stream>>>(W_ffn_1, 2048, 1024, Wt_f1, 2048, 2048, 0);

    // 1) I = f_atoms @ W_i   (pre-relu inp, fp8; K=256 all-A1)
    gemm_f8<true, false, false, false, true><<<dim3(4, 784), 256, 0, stream>>>(
        f_atoms, 133, 256, nullptr, 0, 256, Wt_i, nullptr, nullptr, I, N_ATOMS, HIDDEN);
    // 2) Y = gather-sum(relu(I))
    gather_f8<true><<<N_ATOMS / 8, 256, 0, stream>>>(I, a_nei, Y);
    // 3) I = relu(I + Y @ W_h)   (in-place addm; K=512 -> 4 iters)
    gemm_f8<false, true, false, true, true><<<dim3(4, 784), 256, 0, stream>>>(
        nullptr, 0, 0, Y, 512, 512, Wch, nullptr, I, I, N_ATOMS, HIDDEN);
    // 4) Y = gather-sum(I)
    gather_f8<false><<<N_ATOMS / 8, 256, 0, stream>>>(I, a_nei, Y);
    // 5) I = relu([f_atoms | Y] @ [Wo1 ; Wo2] + b_o)   (K=768 -> 6 iters)
    gemm_f8<true, true, true, false, true><<<dim3(4, 784), 256, 0, stream>>>(
        f_atoms, 133, 256, Y, 512, 768, Wco, b_o, nullptr, I, N_ATOMS, HIDDEN);
    // 6) Mv = segment-mean(I)
    segmean_f8<<<N_MOLS, 256, 0, stream>>>(I, mol_ids, Mv);
    // 7) F = [e1 | e2 | e1*e2]  (bf16)
    feature_kernel<<<N_PAIRS, 128, 0, stream>>>(Mv, edges, F);
    // 8) H1 = relu(F @ Wt_f0^T + b_ffn_i)   (K=1536, bf16)
    gemm_bt<true, true, true><<<dim3(16, 64), 256, 0, stream>>>(
        F, 1536, 1536, Wt_f0, b_ffn_i, H1, N_PAIRS, 2048);
    // 9) H2 = relu(H1 @ W_ffn_1 + b_ffn_1)  (K=2048, bf16)
    gemm_bt<true, true, true><<<dim3(8, 64), 256, 0, stream>>>(
        H1, 2048, 2048, Wt_f1, b_ffn_1, H2, N_PAIRS, 1024);
    // 10) out = sigmoid(H2 @ W_ffn_2 + b_ffn_2)
    final_kernel<<<N_PAIRS, 256, 0, stream>>>(H2, W_ffn_2, b_ffn_2, out);
    (void)in_sizes; (void)n_in; (void)out_size; (void)ws_size;
}